// Round 4
// baseline (15319.875 us; speedup 1.0000x reference)
//
#include <hip/hip_runtime.h>

#define S_TOT 7601
#define BATCH 2
#define BM (BATCH * S_TOT)   // 15202
#define DMODEL 256

typedef unsigned short bf16;

__device__ __forceinline__ float b2f(bf16 u) {
    union { unsigned int i; float f; } v;
    v.i = ((unsigned int)u) << 16;
    return v.f;
}
__device__ __forceinline__ bf16 f2b(float f) {
    union { unsigned int i; float f; } v;
    v.f = f;
    unsigned int r = v.i + 0x7FFFu + ((v.i >> 16) & 1u);
    return (bf16)(r >> 16);
}
__device__ __forceinline__ float ldin(const void* p, size_t i, int isf32) {
    return isf32 ? ((const float*)p)[i] : b2f(((const bf16*)p)[i]);
}

// ---------------- dtype probe ----------------
__global__ void detect_dtype(const unsigned short* __restrict__ src, int* __restrict__ flag) {
    __shared__ int cnt;
    if (threadIdx.x == 0) cnt = 0;
    __syncthreads();
    int local = 0;
    for (int i = threadIdx.x; i < 16384; i += 256) {
        unsigned int e = (src[i] >> 7) & 0xFFu;
        if (e >= 143u) local++;   // |v|>=2^16: never for N(0,1) bf16; ~44% of f32-mantissa halves
    }
    atomicAdd(&cnt, local);
    __syncthreads();
    if (threadIdx.x == 0) *flag = (cnt > 200) ? 1 : 0;
}

// ---------------- pack: [B,C,HW] -> [B,S,C]; x f32, pos bf16 (pos += level_embed[lrow]) ----------------
__global__ void __launch_bounds__(256) pack_level(const void* __restrict__ src,
                                                  const void* __restrict__ pin,
                                                  const void* __restrict__ lemb, int lrow,
                                                  float* __restrict__ x,
                                                  bf16* __restrict__ pout,
                                                  int HW, int start,
                                                  const int* __restrict__ flag) {
    int isf32 = *flag;
    int i = blockIdx.x * 256 + threadIdx.x;
    int total = BATCH * HW * 256;
    if (i >= total) return;
    int c = i & 255;
    int t = i >> 8;
    int s = t % HW;
    int b = t / HW;
    size_t src_idx = ((size_t)b * 256 + c) * HW + s;
    float sv = ldin(src, src_idx, isf32);
    float pv = ldin(pin, src_idx, isf32) + ldin(lemb, (size_t)lrow * 256 + c, isf32);
    size_t o = ((size_t)b * S_TOT + start + s) * 256 + c;
    x[o] = sv;
    pout[o] = f2b(pv);
}

__global__ void __launch_bounds__(256) pack_task(const void* __restrict__ te,
                                                 const void* __restrict__ tpe,
                                                 float* __restrict__ x,
                                                 bf16* __restrict__ pout,
                                                 const int* __restrict__ flag) {
    int isf32 = *flag;
    int i = blockIdx.x * 256 + threadIdx.x;
    int total = BATCH * 20 * 256;
    if (i >= total) return;
    int c = i & 255;
    int t = (i >> 8) % 20;
    int b = (i >> 8) / 20;
    size_t o = ((size_t)b * S_TOT + 7581 + t) * 256 + c;
    x[o] = ldin(te, ((size_t)b * 20 + t) * 256 + c, isf32);
    pout[o] = f2b(ldin(tpe, (size_t)t * 256 + c, isf32));
}

__global__ void __launch_bounds__(256) make_ref(float* __restrict__ ref) {
    int s = blockIdx.x * 256 + threadIdx.x;
    if (s >= S_TOT) return;
    int H, W, st;
    if (s < 5776)      { H = 76; W = 76; st = 0; }
    else if (s < 7220) { H = 38; W = 38; st = 5776; }
    else if (s < 7581) { H = 19; W = 19; st = 7220; }
    else               { H = 1;  W = 20; st = 7581; }
    int r = s - st;
    int i = r / W, j = r % W;
    ref[s * 2 + 0] = (j + 0.5f) / (float)W;
    ref[s * 2 + 1] = (i + 0.5f) / (float)H;
}

__global__ void __launch_bounds__(256) cast_out(const float* __restrict__ x,
                                                void* __restrict__ o, int n,
                                                const int* __restrict__ flag) {
    int isf32 = *flag;
    int i = blockIdx.x * 256 + threadIdx.x;
    if (i >= n) return;
    if (isf32) ((float*)o)[i] = x[i];
    else       ((bf16*)o)[i] = f2b(x[i]);
}

// ---------------- tiled GEMM: C[M,N](bf16) = A[M,K](TA)[+pos] @ W[woff..] + bias[boff..] ----------------
template<typename TA, int ADDPOS, int RELU>
__global__ void __launch_bounds__(256) gemm_bias(const TA* __restrict__ A,
                                                 const bf16* __restrict__ Apos,
                                                 const void* __restrict__ W, size_t woff,
                                                 const void* __restrict__ bias, size_t boff,
                                                 bf16* __restrict__ C,
                                                 int M, int N, int K,
                                                 const int* __restrict__ flag) {
    int isf32 = *flag;
    __shared__ float As[16][65];
    __shared__ float Bs[16][65];
    int tid = threadIdx.x;
    int tx = tid & 15;
    int ty = tid >> 4;
    int bm = blockIdx.y * 64;
    int bn = blockIdx.x * 64;
    float acc[4][4] = {};
    for (int k0 = 0; k0 < K; k0 += 16) {
#pragma unroll
        for (int e = 0; e < 4; ++e) {
            int idx = tid + e * 256;
            int mm = idx >> 4;
            int kk = idx & 15;
            int gm = bm + mm;
            float av = 0.f;
            if (gm < M) {
                size_t ai = (size_t)gm * K + k0 + kk;
                if (sizeof(TA) == 4) av = ((const float*)A)[ai];
                else                 av = b2f(((const bf16*)A)[ai]);
                if (ADDPOS) av += b2f(Apos[ai]);
            }
            As[kk][mm] = av;
        }
#pragma unroll
        for (int e = 0; e < 4; ++e) {
            int idx = tid + e * 256;
            int kk = idx >> 6;
            int nn = idx & 63;
            int gn = bn + nn;
            Bs[kk][nn] = (gn < N) ? ldin(W, woff + (size_t)(k0 + kk) * N + gn, isf32) : 0.f;
        }
        __syncthreads();
#pragma unroll
        for (int kk = 0; kk < 16; ++kk) {
            float a[4], b[4];
#pragma unroll
            for (int i = 0; i < 4; ++i) a[i] = As[kk][ty + 16 * i];
#pragma unroll
            for (int j = 0; j < 4; ++j) b[j] = Bs[kk][tx + 16 * j];
#pragma unroll
            for (int i = 0; i < 4; ++i)
#pragma unroll
                for (int j = 0; j < 4; ++j) acc[i][j] += a[i] * b[j];
        }
        __syncthreads();
    }
#pragma unroll
    for (int i = 0; i < 4; ++i) {
        int gm = bm + ty + 16 * i;
        if (gm >= M) continue;
#pragma unroll
        for (int j = 0; j < 4; ++j) {
            int gn = bn + tx + 16 * j;
            if (gn >= N) continue;
            float v = acc[i][j] + ldin(bias, boff + gn, isf32);
            if (RELU) v = fmaxf(v, 0.f);
            C[(size_t)gm * N + gn] = f2b(v);
        }
    }
}

// ---------------- MS-deform sampling (softmax fused), internal bf16 ----------------
__global__ void __launch_bounds__(256) msdeform_sample(const bf16* __restrict__ value,
                                                       const bf16* __restrict__ off,
                                                       const bf16* __restrict__ logits,
                                                       const float* __restrict__ refpts,
                                                       bf16* __restrict__ out) {
    const int LH[4] = {76, 38, 19, 1};
    const int LW[4] = {76, 38, 19, 20};
    const int LS[4] = {0, 5776, 7220, 7581};
    int m = blockIdx.x;
    int b = m / S_TOT;
    int s = m - b * S_TOT;
    int tid = threadIdx.x;
    __shared__ float offs[256];
    __shared__ float attns[128];
    offs[tid] = b2f(off[(size_t)m * 256 + tid]);
    if (tid < 128) attns[tid] = b2f(logits[(size_t)m * 128 + tid]);
    __syncthreads();
    if (tid < 8) {
        float mx = -1e30f;
#pragma unroll
        for (int i = 0; i < 16; ++i) mx = fmaxf(mx, attns[tid * 16 + i]);
        float e[16];
        float sm = 0.f;
#pragma unroll
        for (int i = 0; i < 16; ++i) { e[i] = expf(attns[tid * 16 + i] - mx); sm += e[i]; }
        float inv = 1.f / sm;
#pragma unroll
        for (int i = 0; i < 16; ++i) attns[tid * 16 + i] = e[i] * inv;
    }
    __syncthreads();
    int h = tid >> 5, d = tid & 31;
    float refx = refpts[s * 2 + 0];
    float refy = refpts[s * 2 + 1];
    float acc = 0.f;
    const bf16* vbase = value + (size_t)b * S_TOT * 256;
#pragma unroll
    for (int l = 0; l < 4; ++l) {
        int H = LH[l], W = LW[l], st = LS[l];
        float fW = (float)W, fH = (float)H;
#pragma unroll
        for (int p = 0; p < 4; ++p) {
            int oi = h * 16 + l * 4 + p;
            float ox = offs[oi * 2 + 0];
            float oy = offs[oi * 2 + 1];
            float a = attns[oi];
            float xpix = (refx + ox / fW) * fW - 0.5f;
            float ypix = (refy + oy / fH) * fH - 0.5f;
            float x0f = floorf(xpix), y0f = floorf(ypix);
            int x0 = (int)x0f, y0 = (int)y0f;
            float wx1 = xpix - x0f, wy1 = ypix - y0f;
            float wx0 = 1.f - wx1, wy0 = 1.f - wy1;
            float sval = 0.f;
#pragma unroll
            for (int cy = 0; cy < 2; ++cy) {
                int yi = y0 + cy;
                if (yi < 0 || yi > H - 1) continue;
                float wy = cy ? wy1 : wy0;
#pragma unroll
                for (int cx = 0; cx < 2; ++cx) {
                    int xi = x0 + cx;
                    if (xi < 0 || xi > W - 1) continue;
                    float wx = cx ? wx1 : wx0;
                    sval += wy * wx * b2f(vbase[(size_t)(st + yi * W + xi) * 256 + h * 32 + d]);
                }
            }
            acc += a * sval;
        }
    }
    out[(size_t)m * 256 + tid] = f2b(acc);
}

// ---------------- residual + LayerNorm (in-place into x f32; g/beta external w/ element offset) ----------------
__global__ void __launch_bounds__(256) residual_ln(float* __restrict__ x,
                                                   const bf16* __restrict__ y,
                                                   const void* __restrict__ g, size_t goff,
                                                   const void* __restrict__ beta, size_t boff,
                                                   const int* __restrict__ flag) {
    int isf32 = *flag;
    int m = blockIdx.x;
    int tid = threadIdx.x;
    size_t o = (size_t)m * 256 + tid;
    float r = x[o] + b2f(y[o]);
    __shared__ float red[8];
    float sum = r;
#pragma unroll
    for (int ofs = 32; ofs > 0; ofs >>= 1) sum += __shfl_xor(sum, ofs);
    int wid = tid >> 6;
    if ((tid & 63) == 0) red[wid] = sum;
    __syncthreads();
    float mean = (red[0] + red[1] + red[2] + red[3]) * (1.f / 256.f);
    float dv = r - mean;
    float vv = dv * dv;
#pragma unroll
    for (int ofs = 32; ofs > 0; ofs >>= 1) vv += __shfl_xor(vv, ofs);
    if ((tid & 63) == 0) red[4 + wid] = vv;
    __syncthreads();
    float var = (red[4] + red[5] + red[6] + red[7]) * (1.f / 256.f);
    x[o] = dv * rsqrtf(var + 1e-5f) * ldin(g, goff + tid, isf32) + ldin(beta, boff + tid, isf32);
}

// ---------------- host ----------------
extern "C" void kernel_launch(void* const* d_in, const int* in_sizes, int n_in,
                              void* d_out, int out_size, void* d_ws, size_t ws_size,
                              hipStream_t stream) {
    (void)in_sizes; (void)n_in; (void)out_size; (void)ws_size;
    const size_t MS = (size_t)BM * DMODEL;   // 3,891,712

    char* base = (char*)d_ws;
    int* flag   = (int*)base;    base += 256;
    float* x    = (float*)base;  base += MS * 4;
    bf16* value = (bf16*)base;   base += MS * 2;
    bf16* attnl = (bf16*)base;   base += (size_t)BM * 128 * 2;
    bf16* pos   = (bf16*)base;   base += MS * 2;
    bf16* off   = (bf16*)base;   base += MS * 2;
    bf16* msout = (bf16*)base;   base += MS * 2;
    float* ref  = (float*)base;
    bf16* hidden = value;   // value+attnl contiguous: MS + BM*128 = 5,837,568 bf16 elems
    bf16* yb     = off;
    const int CH = 2850;    // 2850*2048 = 5,836,800 <= 5,837,568

    detect_dtype<<<1, 256, 0, stream>>>((const unsigned short*)d_in[0], flag);

    {
        int HW0 = 76 * 76, HW1 = 38 * 38, HW2 = 19 * 19;
        int n0 = BATCH * HW0 * 256, n1 = BATCH * HW1 * 256, n2 = BATCH * HW2 * 256;
        pack_level<<<(n0 + 255) / 256, 256, 0, stream>>>(d_in[0], d_in[1], d_in[8], 0, x, pos, HW0, 0, flag);
        pack_level<<<(n1 + 255) / 256, 256, 0, stream>>>(d_in[2], d_in[3], d_in[8], 1, x, pos, HW1, 5776, flag);
        pack_level<<<(n2 + 255) / 256, 256, 0, stream>>>(d_in[4], d_in[5], d_in[8], 2, x, pos, HW2, 7220, flag);
        int nt = BATCH * 20 * 256;
        pack_task<<<(nt + 255) / 256, 256, 0, stream>>>(d_in[6], d_in[7], x, pos, flag);
        make_ref<<<(S_TOT + 255) / 256, 256, 0, stream>>>(ref);
    }

    for (int L = 0; L < 6; ++L) {
        size_t oW256 = (size_t)L * 256 * 256, ob256 = (size_t)L * 256;
        size_t oW128 = (size_t)L * 256 * 128, ob128 = (size_t)L * 128;
        size_t oW1   = (size_t)L * 256 * 2048, ob1  = (size_t)L * 2048;
        size_t oW2   = (size_t)L * 2048 * 256;

        dim3 g256(4, (BM + 63) / 64);
        dim3 g128(2, (BM + 63) / 64);
        gemm_bias<float, 0, 0><<<g256, 256, 0, stream>>>(x, nullptr, d_in[13], oW256, d_in[14], ob256,
                                                         value, BM, 256, 256, flag);
        gemm_bias<float, 1, 0><<<g256, 256, 0, stream>>>(x, pos, d_in[9], oW256, d_in[10], ob256,
                                                         off, BM, 256, 256, flag);
        gemm_bias<float, 1, 0><<<g128, 256, 0, stream>>>(x, pos, d_in[11], oW128, d_in[12], ob128,
                                                         attnl, BM, 128, 256, flag);

        msdeform_sample<<<BM, 256, 0, stream>>>(value, off, attnl, ref, msout);

        gemm_bias<bf16, 0, 0><<<g256, 256, 0, stream>>>(msout, nullptr, d_in[15], oW256, d_in[16], ob256,
                                                        yb, BM, 256, 256, flag);
        residual_ln<<<BM, 256, 0, stream>>>(x, yb, d_in[21], ob256, d_in[22], ob256, flag);

        for (int r0 = 0; r0 < BM; r0 += CH) {
            int mc = BM - r0 < CH ? BM - r0 : CH;
            dim3 gh(32, (mc + 63) / 64);
            dim3 go(4, (mc + 63) / 64);
            gemm_bias<float, 0, 1><<<gh, 256, 0, stream>>>(x + (size_t)r0 * 256, nullptr, d_in[17], oW1,
                                                           d_in[18], ob1, hidden, mc, 2048, 256, flag);
            gemm_bias<bf16, 0, 0><<<go, 256, 0, stream>>>(hidden, nullptr, d_in[19], oW2, d_in[20], ob256,
                                                          yb + (size_t)r0 * 256, mc, 256, 2048, flag);
        }
        residual_ln<<<BM, 256, 0, stream>>>(x, yb, d_in[23], ob256, d_in[24], ob256, flag);
    }

    cast_out<<<((int)MS + 255) / 256, 256, 0, stream>>>(x, d_out, (int)MS, flag);
}

// Round 5
// 2534.935 us; speedup vs baseline: 6.0435x; 6.0435x over previous
//
#include <hip/hip_runtime.h>

#define S_TOT 7601
#define BATCH 2
#define BM (BATCH * S_TOT)   // 15202
#define DMODEL 256

typedef unsigned short bf16;
typedef __attribute__((ext_vector_type(8))) short v8s;
typedef __attribute__((ext_vector_type(4))) float v4f;

__device__ __forceinline__ float b2f(bf16 u) {
    union { unsigned int i; float f; } v;
    v.i = ((unsigned int)u) << 16;
    return v.f;
}
__device__ __forceinline__ bf16 f2b(float f) {
    union { unsigned int i; float f; } v;
    v.f = f;
    unsigned int r = v.i + 0x7FFFu + ((v.i >> 16) & 1u);
    return (bf16)(r >> 16);
}
__device__ __forceinline__ float ldin(const void* p, size_t i, int isf32) {
    return isf32 ? ((const float*)p)[i] : b2f(((const bf16*)p)[i]);
}

// ---------------- dtype probe ----------------
__global__ void detect_dtype(const unsigned short* __restrict__ src, int* __restrict__ flag) {
    __shared__ int cnt;
    if (threadIdx.x == 0) cnt = 0;
    __syncthreads();
    int local = 0;
    for (int i = threadIdx.x; i < 16384; i += 256) {
        unsigned int e = (src[i] >> 7) & 0xFFu;
        if (e >= 143u) local++;
    }
    atomicAdd(&cnt, local);
    __syncthreads();
    if (threadIdx.x == 0) *flag = (cnt > 200) ? 1 : 0;
}

// ---------------- pack ----------------
__global__ void __launch_bounds__(256) pack_level(const void* __restrict__ src,
                                                  const void* __restrict__ pin,
                                                  const void* __restrict__ lemb, int lrow,
                                                  float* __restrict__ x,
                                                  bf16* __restrict__ pout,
                                                  int HW, int start,
                                                  const int* __restrict__ flag) {
    int isf32 = *flag;
    int i = blockIdx.x * 256 + threadIdx.x;
    int total = BATCH * HW * 256;
    if (i >= total) return;
    int c = i & 255;
    int t = i >> 8;
    int s = t % HW;
    int b = t / HW;
    size_t src_idx = ((size_t)b * 256 + c) * HW + s;
    float sv = ldin(src, src_idx, isf32);
    float pv = ldin(pin, src_idx, isf32) + ldin(lemb, (size_t)lrow * 256 + c, isf32);
    size_t o = ((size_t)b * S_TOT + start + s) * 256 + c;
    x[o] = sv;
    pout[o] = f2b(pv);
}

__global__ void __launch_bounds__(256) pack_task(const void* __restrict__ te,
                                                 const void* __restrict__ tpe,
                                                 float* __restrict__ x,
                                                 bf16* __restrict__ pout,
                                                 const int* __restrict__ flag) {
    int isf32 = *flag;
    int i = blockIdx.x * 256 + threadIdx.x;
    int total = BATCH * 20 * 256;
    if (i >= total) return;
    int c = i & 255;
    int t = (i >> 8) % 20;
    int b = (i >> 8) / 20;
    size_t o = ((size_t)b * S_TOT + 7581 + t) * 256 + c;
    x[o] = ldin(te, ((size_t)b * 20 + t) * 256 + c, isf32);
    pout[o] = f2b(ldin(tpe, (size_t)t * 256 + c, isf32));
}

__global__ void __launch_bounds__(256) make_ref(float* __restrict__ ref) {
    int s = blockIdx.x * 256 + threadIdx.x;
    if (s >= S_TOT) return;
    int H, W, st;
    if (s < 5776)      { H = 76; W = 76; st = 0; }
    else if (s < 7220) { H = 38; W = 38; st = 5776; }
    else if (s < 7581) { H = 19; W = 19; st = 7220; }
    else               { H = 1;  W = 20; st = 7581; }
    int r = s - st;
    int i = r / W, j = r % W;
    ref[s * 2 + 0] = (j + 0.5f) / (float)W;
    ref[s * 2 + 1] = (i + 0.5f) / (float)H;
}

__global__ void __launch_bounds__(256) cast_out(const float* __restrict__ x,
                                                void* __restrict__ o, int n,
                                                const int* __restrict__ flag) {
    int isf32 = *flag;
    int i = blockIdx.x * 256 + threadIdx.x;
    if (i >= n) return;
    if (isf32) ((float*)o)[i] = x[i];
    else       ((bf16*)o)[i] = f2b(x[i]);
}

// ---------------- cvt: xb = bf16(x); optional qb = bf16(x + pos) ----------------
__global__ void __launch_bounds__(256) cvt_xq(const float* __restrict__ x,
                                              const bf16* __restrict__ pos,
                                              bf16* __restrict__ xb,
                                              bf16* __restrict__ qb, int n4) {
    int i = blockIdx.x * 256 + threadIdx.x;
    if (i >= n4) return;
    float4 xv = ((const float4*)x)[i];
    ushort4 xo;
    xo.x = f2b(xv.x); xo.y = f2b(xv.y); xo.z = f2b(xv.z); xo.w = f2b(xv.w);
    ((ushort4*)xb)[i] = xo;
    if (qb) {
        ushort4 pv = ((const ushort4*)pos)[i];
        ushort4 qo;
        qo.x = f2b(xv.x + b2f(pv.x));
        qo.y = f2b(xv.y + b2f(pv.y));
        qo.z = f2b(xv.z + b2f(pv.z));
        qo.w = f2b(xv.w + b2f(pv.w));
        ((ushort4*)qb)[i] = qo;
    }
}

// ---------------- weight transpose+convert: W[K][N] (ext dtype) -> Wt[N][K] bf16 ----------------
__global__ void __launch_bounds__(256) transpose_w(const void* __restrict__ W, size_t woff,
                                                   bf16* __restrict__ Wt, int K, int N,
                                                   const int* __restrict__ flag) {
    int isf32 = *flag;
    __shared__ float tl[32][33];
    int tk = blockIdx.y * 32;
    int tn = blockIdx.x * 32;
    int r = threadIdx.x >> 3;
    int c4 = (threadIdx.x & 7) * 4;
#pragma unroll
    for (int i = 0; i < 4; ++i)
        tl[r][c4 + i] = ldin(W, woff + (size_t)(tk + r) * N + tn + c4 + i, isf32);
    __syncthreads();
#pragma unroll
    for (int i = 0; i < 4; ++i)
        Wt[(size_t)(tn + r) * K + tk + c4 + i] = f2b(tl[c4 + i][r]);
}

// ---------------- MFMA GEMM: C[M,N](bf16) = A[M,K](bf16) @ Wt[N,K](bf16)^T + bias ----------------
// 128x128 tile, 4 waves, BK=32, 16x16x32 bf16 MFMA.
__global__ void __launch_bounds__(256) mfma_gemm(const bf16* __restrict__ A,
                                                 const bf16* __restrict__ Wt,
                                                 const void* __restrict__ bias, size_t boff,
                                                 bf16* __restrict__ C,
                                                 int M, int N, int K, int relu,
                                                 const int* __restrict__ flag) {
    int isf32 = *flag;
    __shared__ __align__(16) bf16 As[128 * 32];
    __shared__ __align__(16) bf16 Bs[128 * 40];   // +8 pad: 80B rows, 16B-aligned
    int tid = threadIdx.x;
    int lane = tid & 63, wave = tid >> 6;
    int wm = (wave & 1) << 6, wn = (wave >> 1) << 6;
    int bm = blockIdx.y * 128, bn = blockIdx.x * 128;
    int q = lane >> 4, l15 = lane & 15;

    v4f acc[4][4];
#pragma unroll
    for (int i = 0; i < 4; ++i)
#pragma unroll
        for (int j = 0; j < 4; ++j) acc[i][j] = (v4f){0.f, 0.f, 0.f, 0.f};

    int ar = tid >> 2;            // A: row within half (0..63)
    int ak = (tid & 3) * 8;       // A: k offset
    int brow = tid >> 1;          // B: n row (0..127)
    int bkh = (tid & 1) * 16;     // B: k half

    for (int k0 = 0; k0 < K; k0 += 32) {
        // ---- stage A (128x32) ----
#pragma unroll
        for (int h = 0; h < 2; ++h) {
            int row = ar + 64 * h;
            int gm = bm + row;
            uint4 av = make_uint4(0, 0, 0, 0);
            if (gm < M) av = *(const uint4*)(A + (size_t)gm * K + k0 + ak);
            *(uint4*)&As[row * 32 + ak] = av;
        }
        // ---- stage B (128n x 32k) from Wt[N][K] ----
        {
            const bf16* wrow = Wt + (size_t)(bn + brow) * K + k0 + bkh;
            uint4 w0 = *(const uint4*)wrow;
            uint4 w1 = *(const uint4*)(wrow + 8);
            *(uint4*)&Bs[brow * 40 + bkh] = w0;
            *(uint4*)&Bs[brow * 40 + bkh + 8] = w1;
        }
        __syncthreads();
        v8s a_frag[4], b_frag[4];
#pragma unroll
        for (int mi = 0; mi < 4; ++mi)
            a_frag[mi] = *(const v8s*)&As[(wm + mi * 16 + l15) * 32 + q * 8];
#pragma unroll
        for (int ni = 0; ni < 4; ++ni)
            b_frag[ni] = *(const v8s*)&Bs[(wn + ni * 16 + l15) * 40 + q * 8];
#pragma unroll
        for (int mi = 0; mi < 4; ++mi)
#pragma unroll
            for (int ni = 0; ni < 4; ++ni)
                acc[mi][ni] = __builtin_amdgcn_mfma_f32_16x16x32_bf16(
                    a_frag[mi], b_frag[ni], acc[mi][ni], 0, 0, 0);
        __syncthreads();
    }

    // ---- epilogue ----
#pragma unroll
    for (int ni = 0; ni < 4; ++ni) {
        int gn = bn + wn + ni * 16 + l15;
        float bv = ldin(bias, boff + gn, isf32);
#pragma unroll
        for (int mi = 0; mi < 4; ++mi) {
#pragma unroll
            for (int r = 0; r < 4; ++r) {
                int gm = bm + wm + mi * 16 + q * 4 + r;
                if (gm < M) {
                    float v = acc[mi][ni][r] + bv;
                    if (relu) v = fmaxf(v, 0.f);
                    C[(size_t)gm * N + gn] = f2b(v);
                }
            }
        }
    }
}

// ---------------- fallback VALU GEMM (round-4 proven) ----------------
template<typename TA, int ADDPOS, int RELU>
__global__ void __launch_bounds__(256) gemm_bias(const TA* __restrict__ A,
                                                 const bf16* __restrict__ Apos,
                                                 const void* __restrict__ W, size_t woff,
                                                 const void* __restrict__ bias, size_t boff,
                                                 bf16* __restrict__ C,
                                                 int M, int N, int K,
                                                 const int* __restrict__ flag) {
    int isf32 = *flag;
    __shared__ float As[16][65];
    __shared__ float Bs[16][65];
    int tid = threadIdx.x;
    int tx = tid & 15;
    int ty = tid >> 4;
    int bm = blockIdx.y * 64;
    int bn = blockIdx.x * 64;
    float acc[4][4] = {};
    for (int k0 = 0; k0 < K; k0 += 16) {
#pragma unroll
        for (int e = 0; e < 4; ++e) {
            int idx = tid + e * 256;
            int mm = idx >> 4;
            int kk = idx & 15;
            int gm = bm + mm;
            float av = 0.f;
            if (gm < M) {
                size_t ai = (size_t)gm * K + k0 + kk;
                if (sizeof(TA) == 4) av = ((const float*)A)[ai];
                else                 av = b2f(((const bf16*)A)[ai]);
                if (ADDPOS) av += b2f(Apos[ai]);
            }
            As[kk][mm] = av;
        }
#pragma unroll
        for (int e = 0; e < 4; ++e) {
            int idx = tid + e * 256;
            int kk = idx >> 6;
            int nn = idx & 63;
            int gn = bn + nn;
            Bs[kk][nn] = (gn < N) ? ldin(W, woff + (size_t)(k0 + kk) * N + gn, isf32) : 0.f;
        }
        __syncthreads();
#pragma unroll
        for (int kk = 0; kk < 16; ++kk) {
            float a[4], b[4];
#pragma unroll
            for (int i = 0; i < 4; ++i) a[i] = As[kk][ty + 16 * i];
#pragma unroll
            for (int j = 0; j < 4; ++j) b[j] = Bs[kk][tx + 16 * j];
#pragma unroll
            for (int i = 0; i < 4; ++i)
#pragma unroll
                for (int j = 0; j < 4; ++j) acc[i][j] += a[i] * b[j];
        }
        __syncthreads();
    }
#pragma unroll
    for (int i = 0; i < 4; ++i) {
        int gm = bm + ty + 16 * i;
        if (gm >= M) continue;
#pragma unroll
        for (int j = 0; j < 4; ++j) {
            int gn = bn + tx + 16 * j;
            if (gn >= N) continue;
            float v = acc[i][j] + ldin(bias, boff + gn, isf32);
            if (RELU) v = fmaxf(v, 0.f);
            C[(size_t)gm * N + gn] = f2b(v);
        }
    }
}

// ---------------- MS-deform sampling (softmax fused); out may alias off (row-local) ----------------
__global__ void __launch_bounds__(256) msdeform_sample(const bf16* __restrict__ value,
                                                       const bf16* __restrict__ off,
                                                       const bf16* __restrict__ logits,
                                                       const float* __restrict__ refpts,
                                                       bf16* __restrict__ out) {
    const int LH[4] = {76, 38, 19, 1};
    const int LW[4] = {76, 38, 19, 20};
    const int LS[4] = {0, 5776, 7220, 7581};
    int m = blockIdx.x;
    int b = m / S_TOT;
    int s = m - b * S_TOT;
    int tid = threadIdx.x;
    __shared__ float offs[256];
    __shared__ float attns[128];
    offs[tid] = b2f(off[(size_t)m * 256 + tid]);
    if (tid < 128) attns[tid] = b2f(logits[(size_t)m * 128 + tid]);
    __syncthreads();
    if (tid < 8) {
        float mx = -1e30f;
#pragma unroll
        for (int i = 0; i < 16; ++i) mx = fmaxf(mx, attns[tid * 16 + i]);
        float e[16];
        float sm = 0.f;
#pragma unroll
        for (int i = 0; i < 16; ++i) { e[i] = expf(attns[tid * 16 + i] - mx); sm += e[i]; }
        float inv = 1.f / sm;
#pragma unroll
        for (int i = 0; i < 16; ++i) attns[tid * 16 + i] = e[i] * inv;
    }
    __syncthreads();
    int h = tid >> 5, d = tid & 31;
    float refx = refpts[s * 2 + 0];
    float refy = refpts[s * 2 + 1];
    float acc = 0.f;
    const bf16* vbase = value + (size_t)b * S_TOT * 256;
#pragma unroll
    for (int l = 0; l < 4; ++l) {
        int H = LH[l], W = LW[l], st = LS[l];
        float fW = (float)W, fH = (float)H;
#pragma unroll
        for (int p = 0; p < 4; ++p) {
            int oi = h * 16 + l * 4 + p;
            float ox = offs[oi * 2 + 0];
            float oy = offs[oi * 2 + 1];
            float a = attns[oi];
            float xpix = (refx + ox / fW) * fW - 0.5f;
            float ypix = (refy + oy / fH) * fH - 0.5f;
            float x0f = floorf(xpix), y0f = floorf(ypix);
            int x0 = (int)x0f, y0 = (int)y0f;
            float wx1 = xpix - x0f, wy1 = ypix - y0f;
            float wx0 = 1.f - wx1, wy0 = 1.f - wy1;
            float sval = 0.f;
#pragma unroll
            for (int cy = 0; cy < 2; ++cy) {
                int yi = y0 + cy;
                if (yi < 0 || yi > H - 1) continue;
                float wy = cy ? wy1 : wy0;
#pragma unroll
                for (int cx = 0; cx < 2; ++cx) {
                    int xi = x0 + cx;
                    if (xi < 0 || xi > W - 1) continue;
                    float wx = cx ? wx1 : wx0;
                    sval += wy * wx * b2f(vbase[(size_t)(st + yi * W + xi) * 256 + h * 32 + d]);
                }
            }
            acc += a * sval;
        }
    }
    out[(size_t)m * 256 + tid] = f2b(acc);
}

// ---------------- residual + LayerNorm ----------------
__global__ void __launch_bounds__(256) residual_ln(float* __restrict__ x,
                                                   const bf16* __restrict__ y,
                                                   const void* __restrict__ g, size_t goff,
                                                   const void* __restrict__ beta, size_t boff,
                                                   const int* __restrict__ flag) {
    int isf32 = *flag;
    int m = blockIdx.x;
    int tid = threadIdx.x;
    size_t o = (size_t)m * 256 + tid;
    float r = x[o] + b2f(y[o]);
    __shared__ float red[8];
    float sum = r;
#pragma unroll
    for (int ofs = 32; ofs > 0; ofs >>= 1) sum += __shfl_xor(sum, ofs);
    int wid = tid >> 6;
    if ((tid & 63) == 0) red[wid] = sum;
    __syncthreads();
    float mean = (red[0] + red[1] + red[2] + red[3]) * (1.f / 256.f);
    float dv = r - mean;
    float vv = dv * dv;
#pragma unroll
    for (int ofs = 32; ofs > 0; ofs >>= 1) vv += __shfl_xor(vv, ofs);
    if ((tid & 63) == 0) red[4 + wid] = vv;
    __syncthreads();
    float var = (red[4] + red[5] + red[6] + red[7]) * (1.f / 256.f);
    x[o] = dv * rsqrtf(var + 1e-5f) * ldin(g, goff + tid, isf32) + ldin(beta, boff + tid, isf32);
}

// ---------------- host ----------------
extern "C" void kernel_launch(void* const* d_in, const int* in_sizes, int n_in,
                              void* d_out, int out_size, void* d_ws, size_t ws_size,
                              hipStream_t stream) {
    (void)in_sizes; (void)n_in; (void)out_size;
    const size_t MS = (size_t)BM * DMODEL;   // 3,891,712

    char* base = (char*)d_ws;
    int* flag    = (int*)base;    base += 256;
    float* x     = (float*)base;  base += MS * 4;
    bf16* value  = (bf16*)base;   base += MS * 2;
    bf16* attnl  = (bf16*)base;   base += (size_t)BM * 128 * 2;
    bf16* pos    = (bf16*)base;   base += MS * 2;
    bf16* offms  = (bf16*)base;   base += MS * 2;   // off, then msout in-place
    bf16* yb     = (bf16*)base;   base += MS * 2;   // also qb in fast path
    size_t base_used = (size_t)(base - (char*)d_ws);

    // fast-path extras
    bf16* xb = (bf16*)base;
    size_t need_fast = base_used + MS * 2                          // xb
                     + (size_t)2048 * 256 * 2 * 2                  // W1t, W2t
                     + (size_t)256 * 256 * 2 * 3                   // Wvt, Wofft, Wot
                     + (size_t)128 * 256 * 2                       // Wat
                     + (size_t)S_TOT * 2 * 4 + 1024;               // ref
    bool FAST = ws_size >= need_fast;

    bf16 *W1t = nullptr, *W2t = nullptr, *Wvt = nullptr, *Wofft = nullptr, *Wot = nullptr, *Wat = nullptr;
    float* ref;
    bf16* hiddenF = nullptr;
    bool FULLH = false;
    if (FAST) {
        char* p = (char*)xb + MS * 2;
        W1t = (bf16*)p;   p += (size_t)2048 * 256 * 2;
        W2t = (bf16*)p;   p += (size_t)2048 * 256 * 2;
        Wvt = (bf16*)p;   p += (size_t)256 * 256 * 2;
        Wofft = (bf16*)p; p += (size_t)256 * 256 * 2;
        Wot = (bf16*)p;   p += (size_t)256 * 256 * 2;
        Wat = (bf16*)p;   p += (size_t)128 * 256 * 2;
        ref = (float*)p;  p += (size_t)S_TOT * 2 * 4;
        size_t used = (size_t)(p - (char*)d_ws);
        used = (used + 255) & ~(size_t)255;
        if (ws_size >= used + (size_t)BM * 2048 * 2) {
            hiddenF = (bf16*)((char*)d_ws + used);
            FULLH = true;
        }
    } else {
        ref = (float*)base;
    }

    bf16* hidden = FULLH ? hiddenF : value;    // chunked: alias value+attnl (5,837,568 elems)
    const int CH = FULLH ? BM : 2816;          // 2816*2048 = 5,767,168 <= 5,837,568

    detect_dtype<<<1, 256, 0, stream>>>((const unsigned short*)d_in[0], flag);

    {
        int HW0 = 76 * 76, HW1 = 38 * 38, HW2 = 19 * 19;
        int n0 = BATCH * HW0 * 256, n1 = BATCH * HW1 * 256, n2 = BATCH * HW2 * 256;
        pack_level<<<(n0 + 255) / 256, 256, 0, stream>>>(d_in[0], d_in[1], d_in[8], 0, x, pos, HW0, 0, flag);
        pack_level<<<(n1 + 255) / 256, 256, 0, stream>>>(d_in[2], d_in[3], d_in[8], 1, x, pos, HW1, 5776, flag);
        pack_level<<<(n2 + 255) / 256, 256, 0, stream>>>(d_in[4], d_in[5], d_in[8], 2, x, pos, HW2, 7220, flag);
        int nt = BATCH * 20 * 256;
        pack_task<<<(nt + 255) / 256, 256, 0, stream>>>(d_in[6], d_in[7], x, pos, flag);
        make_ref<<<(S_TOT + 255) / 256, 256, 0, stream>>>(ref);
    }

    const int GM = (BM + 127) / 128;   // 119
    const int n4 = (int)(MS / 4);

    for (int L = 0; L < 6; ++L) {
        size_t oW256 = (size_t)L * 256 * 256, ob256 = (size_t)L * 256;
        size_t oW128 = (size_t)L * 256 * 128, ob128 = (size_t)L * 128;
        size_t oW1   = (size_t)L * 256 * 2048, ob1  = (size_t)L * 2048;
        size_t oW2   = (size_t)L * 2048 * 256;

        if (FAST) {
            dim3 t256(8, 8), t128a(4, 8), tW1(64, 8), tW2(8, 64);
            transpose_w<<<t256, 256, 0, stream>>>(d_in[13], oW256, Wvt, 256, 256, flag);
            transpose_w<<<t256, 256, 0, stream>>>(d_in[9],  oW256, Wofft, 256, 256, flag);
            transpose_w<<<t128a, 256, 0, stream>>>(d_in[11], oW128, Wat, 256, 128, flag);
            transpose_w<<<t256, 256, 0, stream>>>(d_in[15], oW256, Wot, 256, 256, flag);
            transpose_w<<<tW1, 256, 0, stream>>>(d_in[17], oW1, W1t, 256, 2048, flag);
            transpose_w<<<tW2, 256, 0, stream>>>(d_in[19], oW2, W2t, 2048, 256, flag);

            bf16* qb = yb;
            cvt_xq<<<(n4 + 255) / 256, 256, 0, stream>>>(x, pos, xb, qb, n4);

            mfma_gemm<<<dim3(2, GM), 256, 0, stream>>>(xb, Wvt, d_in[14], ob256, value, BM, 256, 256, 0, flag);
            mfma_gemm<<<dim3(2, GM), 256, 0, stream>>>(qb, Wofft, d_in[10], ob256, offms, BM, 256, 256, 0, flag);
            mfma_gemm<<<dim3(1, GM), 256, 0, stream>>>(qb, Wat, d_in[12], ob128, attnl, BM, 128, 256, 0, flag);

            msdeform_sample<<<BM, 256, 0, stream>>>(value, offms, attnl, ref, offms);

            mfma_gemm<<<dim3(2, GM), 256, 0, stream>>>(offms, Wot, d_in[16], ob256, yb, BM, 256, 256, 0, flag);
            residual_ln<<<BM, 256, 0, stream>>>(x, yb, d_in[21], ob256, d_in[22], ob256, flag);

            cvt_xq<<<(n4 + 255) / 256, 256, 0, stream>>>(x, nullptr, xb, nullptr, n4);
            for (int r0 = 0; r0 < BM; r0 += CH) {
                int mc = BM - r0 < CH ? BM - r0 : CH;
                int gmc = (mc + 127) / 128;
                mfma_gemm<<<dim3(16, gmc), 256, 0, stream>>>(xb + (size_t)r0 * 256, W1t, d_in[18], ob1,
                                                             hidden, mc, 2048, 256, 1, flag);
                mfma_gemm<<<dim3(2, gmc), 256, 0, stream>>>(hidden, W2t, d_in[20], ob256,
                                                            yb + (size_t)r0 * 256, mc, 256, 2048, 0, flag);
            }
            residual_ln<<<BM, 256, 0, stream>>>(x, yb, d_in[23], ob256, d_in[24], ob256, flag);
        } else {
            dim3 g256(4, (BM + 63) / 64);
            dim3 g128(2, (BM + 63) / 64);
            gemm_bias<float, 0, 0><<<g256, 256, 0, stream>>>(x, nullptr, d_in[13], oW256, d_in[14], ob256,
                                                             value, BM, 256, 256, flag);
            gemm_bias<float, 1, 0><<<g256, 256, 0, stream>>>(x, pos, d_in[9], oW256, d_in[10], ob256,
                                                             offms, BM, 256, 256, flag);
            gemm_bias<float, 1, 0><<<g128, 256, 0, stream>>>(x, pos, d_in[11], oW128, d_in[12], ob128,
                                                             attnl, BM, 128, 256, flag);
            msdeform_sample<<<BM, 256, 0, stream>>>(value, offms, attnl, ref, offms);
            gemm_bias<bf16, 0, 0><<<g256, 256, 0, stream>>>(offms, nullptr, d_in[15], oW256, d_in[16], ob256,
                                                            yb, BM, 256, 256, flag);
            residual_ln<<<BM, 256, 0, stream>>>(x, yb, d_in[21], ob256, d_in[22], ob256, flag);
            for (int r0 = 0; r0 < BM; r0 += CH) {
                int mc = BM - r0 < CH ? BM - r0 : CH;
                dim3 gh(32, (mc + 63) / 64);
                dim3 go(4, (mc + 63) / 64);
                gemm_bias<float, 0, 1><<<gh, 256, 0, stream>>>(x + (size_t)r0 * 256, nullptr, d_in[17], oW1,
                                                               d_in[18], ob1, hidden, mc, 2048, 256, flag);
                gemm_bias<bf16, 0, 0><<<go, 256, 0, stream>>>(hidden, nullptr, d_in[19], oW2, d_in[20], ob256,
                                                              yb + (size_t)r0 * 256, mc, 256, 2048, flag);
            }
            residual_ln<<<BM, 256, 0, stream>>>(x, yb, d_in[23], ob256, d_in[24], ob256, flag);
        }
    }

    cast_out<<<((int)MS + 255) / 256, 256, 0, stream>>>(x, d_out, (int)MS, flag);
}

// Round 6
// 1882.521 us; speedup vs baseline: 8.1380x; 1.3466x over previous
//
#include <hip/hip_runtime.h>

#define S_TOT 7601
#define BATCH 2
#define BM (BATCH * S_TOT)   // 15202
#define DMODEL 256

typedef unsigned short bf16;
typedef __attribute__((ext_vector_type(8))) short v8s;
typedef __attribute__((ext_vector_type(4))) float v4f;

__device__ __forceinline__ float b2f(bf16 u) {
    union { unsigned int i; float f; } v;
    v.i = ((unsigned int)u) << 16;
    return v.f;
}
__device__ __forceinline__ bf16 f2b(float f) {
    union { unsigned int i; float f; } v;
    v.f = f;
    unsigned int r = v.i + 0x7FFFu + ((v.i >> 16) & 1u);
    return (bf16)(r >> 16);
}
__device__ __forceinline__ float ldin(const void* p, size_t i, int isf32) {
    return isf32 ? ((const float*)p)[i] : b2f(((const bf16*)p)[i]);
}

// ---------------- dtype probe ----------------
__global__ void detect_dtype(const unsigned short* __restrict__ src, int* __restrict__ flag) {
    __shared__ int cnt;
    if (threadIdx.x == 0) cnt = 0;
    __syncthreads();
    int local = 0;
    for (int i = threadIdx.x; i < 16384; i += 256) {
        unsigned int e = (src[i] >> 7) & 0xFFu;
        if (e >= 143u) local++;
    }
    atomicAdd(&cnt, local);
    __syncthreads();
    if (threadIdx.x == 0) *flag = (cnt > 200) ? 1 : 0;
}

// ---------------- pack ----------------
__global__ void __launch_bounds__(256) pack_level(const void* __restrict__ src,
                                                  const void* __restrict__ pin,
                                                  const void* __restrict__ lemb, int lrow,
                                                  float* __restrict__ x,
                                                  bf16* __restrict__ pout,
                                                  int HW, int start,
                                                  const int* __restrict__ flag) {
    int isf32 = *flag;
    int i = blockIdx.x * 256 + threadIdx.x;
    int total = BATCH * HW * 256;
    if (i >= total) return;
    int c = i & 255;
    int t = i >> 8;
    int s = t % HW;
    int b = t / HW;
    size_t src_idx = ((size_t)b * 256 + c) * HW + s;
    float sv = ldin(src, src_idx, isf32);
    float pv = ldin(pin, src_idx, isf32) + ldin(lemb, (size_t)lrow * 256 + c, isf32);
    size_t o = ((size_t)b * S_TOT + start + s) * 256 + c;
    x[o] = sv;
    pout[o] = f2b(pv);
}

__global__ void __launch_bounds__(256) pack_task(const void* __restrict__ te,
                                                 const void* __restrict__ tpe,
                                                 float* __restrict__ x,
                                                 bf16* __restrict__ pout,
                                                 const int* __restrict__ flag) {
    int isf32 = *flag;
    int i = blockIdx.x * 256 + threadIdx.x;
    int total = BATCH * 20 * 256;
    if (i >= total) return;
    int c = i & 255;
    int t = (i >> 8) % 20;
    int b = (i >> 8) / 20;
    size_t o = ((size_t)b * S_TOT + 7581 + t) * 256 + c;
    x[o] = ldin(te, ((size_t)b * 20 + t) * 256 + c, isf32);
    pout[o] = f2b(ldin(tpe, (size_t)t * 256 + c, isf32));
}

__global__ void __launch_bounds__(256) make_ref(float* __restrict__ ref) {
    int s = blockIdx.x * 256 + threadIdx.x;
    if (s >= S_TOT) return;
    int H, W, st;
    if (s < 5776)      { H = 76; W = 76; st = 0; }
    else if (s < 7220) { H = 38; W = 38; st = 5776; }
    else if (s < 7581) { H = 19; W = 19; st = 7220; }
    else               { H = 1;  W = 20; st = 7581; }
    int r = s - st;
    int i = r / W, j = r % W;
    ref[s * 2 + 0] = (j + 0.5f) / (float)W;
    ref[s * 2 + 1] = (i + 0.5f) / (float)H;
}

__global__ void __launch_bounds__(256) cast_out(const float* __restrict__ x,
                                                void* __restrict__ o, int n,
                                                const int* __restrict__ flag) {
    int isf32 = *flag;
    int i = blockIdx.x * 256 + threadIdx.x;
    if (i >= n) return;
    if (isf32) ((float*)o)[i] = x[i];
    else       ((bf16*)o)[i] = f2b(x[i]);
}

// ---------------- cvt: xb = bf16(x) ----------------
__global__ void __launch_bounds__(256) cvt_x(const float* __restrict__ x,
                                             bf16* __restrict__ xb, int n4) {
    int i = blockIdx.x * 256 + threadIdx.x;
    if (i >= n4) return;
    float4 xv = ((const float4*)x)[i];
    ushort4 xo;
    xo.x = f2b(xv.x); xo.y = f2b(xv.y); xo.z = f2b(xv.z); xo.w = f2b(xv.w);
    ((ushort4*)xb)[i] = xo;
}

// ---------------- cvt: qb = bf16(x + pos) ----------------
__global__ void __launch_bounds__(256) cvt_q(const float* __restrict__ x,
                                             const bf16* __restrict__ pos,
                                             bf16* __restrict__ qb, int n4) {
    int i = blockIdx.x * 256 + threadIdx.x;
    if (i >= n4) return;
    float4 xv = ((const float4*)x)[i];
    ushort4 pv = ((const ushort4*)pos)[i];
    ushort4 qo;
    qo.x = f2b(xv.x + b2f(pv.x));
    qo.y = f2b(xv.y + b2f(pv.y));
    qo.z = f2b(xv.z + b2f(pv.z));
    qo.w = f2b(xv.w + b2f(pv.w));
    ((ushort4*)qb)[i] = qo;
}

// ---------------- weight transpose+convert: W[K][N] (ext dtype) -> Wt[N][K] bf16 ----------------
__global__ void __launch_bounds__(256) transpose_w(const void* __restrict__ W, size_t woff,
                                                   bf16* __restrict__ Wt, int K, int N,
                                                   const int* __restrict__ flag) {
    int isf32 = *flag;
    __shared__ float tl[32][33];
    int tk = blockIdx.y * 32;
    int tn = blockIdx.x * 32;
    int r = threadIdx.x >> 3;
    int c4 = (threadIdx.x & 7) * 4;
#pragma unroll
    for (int i = 0; i < 4; ++i)
        tl[r][c4 + i] = ldin(W, woff + (size_t)(tk + r) * N + tn + c4 + i, isf32);
    __syncthreads();
#pragma unroll
    for (int i = 0; i < 4; ++i)
        Wt[(size_t)(tn + r) * K + tk + c4 + i] = f2b(tl[c4 + i][r]);
}

// ---------------- MFMA GEMM: C[M,N](bf16) = A[M,K](bf16) @ Wt[N,K](bf16)^T + bias ----------------
__global__ void __launch_bounds__(256) mfma_gemm(const bf16* __restrict__ A,
                                                 const bf16* __restrict__ Wt,
                                                 const void* __restrict__ bias, size_t boff,
                                                 bf16* __restrict__ C,
                                                 int M, int N, int K, int relu,
                                                 const int* __restrict__ flag) {
    int isf32 = *flag;
    __shared__ __align__(16) bf16 As[128 * 32];
    __shared__ __align__(16) bf16 Bs[128 * 40];
    int tid = threadIdx.x;
    int lane = tid & 63, wave = tid >> 6;
    int wm = (wave & 1) << 6, wn = (wave >> 1) << 6;
    int bm = blockIdx.y * 128, bn = blockIdx.x * 128;
    int q = lane >> 4, l15 = lane & 15;

    v4f acc[4][4];
#pragma unroll
    for (int i = 0; i < 4; ++i)
#pragma unroll
        for (int j = 0; j < 4; ++j) acc[i][j] = (v4f){0.f, 0.f, 0.f, 0.f};

    int ar = tid >> 2;
    int ak = (tid & 3) * 8;
    int brow = tid >> 1;
    int bkh = (tid & 1) * 16;

    for (int k0 = 0; k0 < K; k0 += 32) {
#pragma unroll
        for (int h = 0; h < 2; ++h) {
            int row = ar + 64 * h;
            int gm = bm + row;
            uint4 av = make_uint4(0, 0, 0, 0);
            if (gm < M) av = *(const uint4*)(A + (size_t)gm * K + k0 + ak);
            *(uint4*)&As[row * 32 + ak] = av;
        }
        {
            const bf16* wrow = Wt + (size_t)(bn + brow) * K + k0 + bkh;
            uint4 w0 = *(const uint4*)wrow;
            uint4 w1 = *(const uint4*)(wrow + 8);
            *(uint4*)&Bs[brow * 40 + bkh] = w0;
            *(uint4*)&Bs[brow * 40 + bkh + 8] = w1;
        }
        __syncthreads();
        v8s a_frag[4], b_frag[4];
#pragma unroll
        for (int mi = 0; mi < 4; ++mi)
            a_frag[mi] = *(const v8s*)&As[(wm + mi * 16 + l15) * 32 + q * 8];
#pragma unroll
        for (int ni = 0; ni < 4; ++ni)
            b_frag[ni] = *(const v8s*)&Bs[(wn + ni * 16 + l15) * 40 + q * 8];
#pragma unroll
        for (int mi = 0; mi < 4; ++mi)
#pragma unroll
            for (int ni = 0; ni < 4; ++ni)
                acc[mi][ni] = __builtin_amdgcn_mfma_f32_16x16x32_bf16(
                    a_frag[mi], b_frag[ni], acc[mi][ni], 0, 0, 0);
        __syncthreads();
    }

#pragma unroll
    for (int ni = 0; ni < 4; ++ni) {
        int gn = bn + wn + ni * 16 + l15;
        float bv = ldin(bias, boff + gn, isf32);
#pragma unroll
        for (int mi = 0; mi < 4; ++mi) {
#pragma unroll
            for (int r = 0; r < 4; ++r) {
                int gm = bm + wm + mi * 16 + q * 4 + r;
                if (gm < M) {
                    float v = acc[mi][ni][r] + bv;
                    if (relu) v = fmaxf(v, 0.f);
                    C[(size_t)gm * N + gn] = f2b(v);
                }
            }
        }
    }
}

// ---------------- fallback VALU GEMM ----------------
template<typename TA, int ADDPOS, int RELU>
__global__ void __launch_bounds__(256) gemm_bias(const TA* __restrict__ A,
                                                 const bf16* __restrict__ Apos,
                                                 const void* __restrict__ W, size_t woff,
                                                 const void* __restrict__ bias, size_t boff,
                                                 bf16* __restrict__ C,
                                                 int M, int N, int K,
                                                 const int* __restrict__ flag) {
    int isf32 = *flag;
    __shared__ float As[16][65];
    __shared__ float Bs[16][65];
    int tid = threadIdx.x;
    int tx = tid & 15;
    int ty = tid >> 4;
    int bm = blockIdx.y * 64;
    int bn = blockIdx.x * 64;
    float acc[4][4] = {};
    for (int k0 = 0; k0 < K; k0 += 16) {
#pragma unroll
        for (int e = 0; e < 4; ++e) {
            int idx = tid + e * 256;
            int mm = idx >> 4;
            int kk = idx & 15;
            int gm = bm + mm;
            float av = 0.f;
            if (gm < M) {
                size_t ai = (size_t)gm * K + k0 + kk;
                if (sizeof(TA) == 4) av = ((const float*)A)[ai];
                else                 av = b2f(((const bf16*)A)[ai]);
                if (ADDPOS) av += b2f(Apos[ai]);
            }
            As[kk][mm] = av;
        }
#pragma unroll
        for (int e = 0; e < 4; ++e) {
            int idx = tid + e * 256;
            int kk = idx >> 6;
            int nn = idx & 63;
            int gn = bn + nn;
            Bs[kk][nn] = (gn < N) ? ldin(W, woff + (size_t)(k0 + kk) * N + gn, isf32) : 0.f;
        }
        __syncthreads();
#pragma unroll
        for (int kk = 0; kk < 16; ++kk) {
            float a[4], b[4];
#pragma unroll
            for (int i = 0; i < 4; ++i) a[i] = As[kk][ty + 16 * i];
#pragma unroll
            for (int j = 0; j < 4; ++j) b[j] = Bs[kk][tx + 16 * j];
#pragma unroll
            for (int i = 0; i < 4; ++i)
#pragma unroll
                for (int j = 0; j < 4; ++j) acc[i][j] += a[i] * b[j];
        }
        __syncthreads();
    }
#pragma unroll
    for (int i = 0; i < 4; ++i) {
        int gm = bm + ty + 16 * i;
        if (gm >= M) continue;
#pragma unroll
        for (int j = 0; j < 4; ++j) {
            int gn = bn + tx + 16 * j;
            if (gn >= N) continue;
            float v = acc[i][j] + ldin(bias, boff + gn, isf32);
            if (RELU) v = fmaxf(v, 0.f);
            C[(size_t)gm * N + gn] = f2b(v);
        }
    }
}

// ---------------- MS-deform sampling v2: 4 rows/block, corner descriptors in LDS ----------------
// out may alias off (block reads its rows' off before writing out rows; rows disjoint across blocks).
__global__ void __launch_bounds__(256) msdeform_sample4(const bf16* __restrict__ value,
                                                        const bf16* __restrict__ off,
                                                        const bf16* __restrict__ logits,
                                                        const float* __restrict__ refpts,
                                                        bf16* __restrict__ out) {
    __shared__ float sAttn[4 * 128];
    __shared__ int2 sIW[4 * 520];   // per row: 8 heads * 65-pitch (64 corners + 1 pad)
    const int LH[4] = {76, 38, 19, 1};
    const int LW[4] = {76, 38, 19, 20};
    const int LS[4] = {0, 5776, 7220, 7581};
    int tid = threadIdx.x;
    int m0 = blockIdx.x * 4;

    // ---- stage logits ----
    for (int i = tid; i < 4 * 128; i += 256) {
        int r = i >> 7, li = i & 127;
        int m = m0 + r;
        int mc = (m < BM) ? m : BM - 1;
        sAttn[i] = b2f(logits[(size_t)mc * 128 + li]);
    }
    __syncthreads();
    // ---- softmax per (row, head): 32 groups of 16 ----
    if (tid < 32) {
        float* g = sAttn + tid * 16;
        float mx = -1e30f;
#pragma unroll
        for (int i = 0; i < 16; ++i) mx = fmaxf(mx, g[i]);
        float e[16], sm = 0.f;
#pragma unroll
        for (int i = 0; i < 16; ++i) { e[i] = __expf(g[i] - mx); sm += e[i]; }
        float inv = 1.f / sm;
#pragma unroll
        for (int i = 0; i < 16; ++i) g[i] = e[i] * inv;
    }
    __syncthreads();
    // ---- corner descriptor setup: 512 point tasks ----
    for (int i = tid; i < 4 * 128; i += 256) {
        int r = i >> 7, oi = i & 127;       // oi = h*16 + l*4 + p
        int m = m0 + r;
        int mc = (m < BM) ? m : BM - 1;
        int b = mc / S_TOT;
        int s = mc - b * S_TOT;
        int h = oi >> 4;
        int l = (oi >> 2) & 3;
        int H = LH[l], W = LW[l], st = LS[l];
        float fW = (float)W, fH = (float)H;
        float refx = refpts[s * 2 + 0];
        float refy = refpts[s * 2 + 1];
        ushort2 ov = *(const ushort2*)(off + (size_t)mc * 256 + oi * 2);
        float a = sAttn[r * 128 + oi];
        float xpix = (refx + b2f(ov.x) / fW) * fW - 0.5f;
        float ypix = (refy + b2f(ov.y) / fH) * fH - 0.5f;
        float x0f = floorf(xpix), y0f = floorf(ypix);
        int x0 = (int)x0f, y0 = (int)y0f;
        float wx1 = xpix - x0f, wy1 = ypix - y0f;
        float wx0 = 1.f - wx1, wy0 = 1.f - wy1;
        int vb = b * (S_TOT * 256) + h * 32;
        int base = r * 520 + h * 65 + (oi & 15) * 4;
#pragma unroll
        for (int c = 0; c < 4; ++c) {
            int cx = c & 1, cy = c >> 1;
            int xi = x0 + cx, yi = y0 + cy;
            float w = (cx ? wx1 : wx0) * (cy ? wy1 : wy0) * a;
            bool valid = (xi >= 0) && (xi <= W - 1) && (yi >= 0) && (yi <= H - 1);
            int xic = min(max(xi, 0), W - 1), yic = min(max(yi, 0), H - 1);
            int2 d;
            d.x = vb + (st + yic * W + xic) * 256;
            d.y = __float_as_int(valid ? w : 0.f);
            sIW[base + c] = d;
        }
    }
    __syncthreads();
    // ---- gather: 4 rows x 64 threads; (h, 4 channels) per thread ----
    int r = tid >> 6, u = tid & 63;
    int h = u >> 3, d4 = (u & 7) * 4;
    int m = m0 + r;
    int cb = r * 520 + h * 65;
    float acc0 = 0.f, acc1 = 0.f, acc2 = 0.f, acc3 = 0.f;
#pragma unroll 8
    for (int c = 0; c < 64; ++c) {
        int2 p = sIW[cb + c];
        float w = __int_as_float(p.y);
        ushort4 v = *(const ushort4*)(value + p.x + d4);
        acc0 += w * b2f(v.x);
        acc1 += w * b2f(v.y);
        acc2 += w * b2f(v.z);
        acc3 += w * b2f(v.w);
    }
    if (m < BM) {
        ushort4 o;
        o.x = f2b(acc0); o.y = f2b(acc1); o.z = f2b(acc2); o.w = f2b(acc3);
        *(ushort4*)(out + (size_t)m * 256 + h * 32 + d4) = o;
    }
}

// ---------------- residual + LayerNorm v2: 4 rows/block, 1 wave/row, optional bf16 mirror ----------------
__global__ void __launch_bounds__(256) residual_ln4(float* __restrict__ x,
                                                    const bf16* __restrict__ y,
                                                    const void* __restrict__ g, size_t goff,
                                                    const void* __restrict__ beta, size_t boff,
                                                    const int* __restrict__ flag,
                                                    bf16* __restrict__ xb) {
    int isf32 = *flag;
    int tid = threadIdx.x;
    int r = tid >> 6, lane = tid & 63;
    int m = blockIdx.x * 4 + r;
    if (m >= BM) return;   // whole-wave uniform exit; no barriers below
    size_t o = (size_t)m * 256 + lane * 4;
    float4 xv = *(const float4*)(x + o);
    ushort4 yv = *(const ushort4*)(y + o);
    float r0 = xv.x + b2f(yv.x), r1 = xv.y + b2f(yv.y);
    float r2 = xv.z + b2f(yv.z), r3 = xv.w + b2f(yv.w);
    float sum = r0 + r1 + r2 + r3;
#pragma unroll
    for (int ofs = 32; ofs > 0; ofs >>= 1) sum += __shfl_xor(sum, ofs);
    float mean = sum * (1.f / 256.f);
    float d0 = r0 - mean, d1 = r1 - mean, d2 = r2 - mean, d3 = r3 - mean;
    float vv = d0 * d0 + d1 * d1 + d2 * d2 + d3 * d3;
#pragma unroll
    for (int ofs = 32; ofs > 0; ofs >>= 1) vv += __shfl_xor(vv, ofs);
    float rstd = rsqrtf(vv * (1.f / 256.f) + 1e-5f);
    int c = lane * 4;
    float o0 = d0 * rstd * ldin(g, goff + c + 0, isf32) + ldin(beta, boff + c + 0, isf32);
    float o1 = d1 * rstd * ldin(g, goff + c + 1, isf32) + ldin(beta, boff + c + 1, isf32);
    float o2 = d2 * rstd * ldin(g, goff + c + 2, isf32) + ldin(beta, boff + c + 2, isf32);
    float o3 = d3 * rstd * ldin(g, goff + c + 3, isf32) + ldin(beta, boff + c + 3, isf32);
    *(float4*)(x + o) = make_float4(o0, o1, o2, o3);
    if (xb) {
        ushort4 xo;
        xo.x = f2b(o0); xo.y = f2b(o1); xo.z = f2b(o2); xo.w = f2b(o3);
        *(ushort4*)(xb + o) = xo;
    }
}

// ---------------- host ----------------
extern "C" void kernel_launch(void* const* d_in, const int* in_sizes, int n_in,
                              void* d_out, int out_size, void* d_ws, size_t ws_size,
                              hipStream_t stream) {
    (void)in_sizes; (void)n_in; (void)out_size;
    const size_t MS = (size_t)BM * DMODEL;   // 3,891,712

    char* base = (char*)d_ws;
    int* flag    = (int*)base;    base += 256;
    float* x     = (float*)base;  base += MS * 4;
    bf16* value  = (bf16*)base;   base += MS * 2;
    bf16* attnl  = (bf16*)base;   base += (size_t)BM * 128 * 2;
    bf16* pos    = (bf16*)base;   base += MS * 2;
    bf16* offms  = (bf16*)base;   base += MS * 2;   // off -> msout in place
    bf16* yb     = (bf16*)base;   base += MS * 2;   // also qb (dead before Wo writes)
    size_t base_used = (size_t)(base - (char*)d_ws);

    bf16* xb = (bf16*)base;
    size_t need_fast = base_used + MS * 2
                     + (size_t)2048 * 256 * 2 * 2
                     + (size_t)256 * 256 * 2 * 3
                     + (size_t)128 * 256 * 2
                     + (size_t)S_TOT * 2 * 4 + 1024;
    bool FAST = ws_size >= need_fast;

    bf16 *W1t = nullptr, *W2t = nullptr, *Wvt = nullptr, *Wofft = nullptr, *Wot = nullptr, *Wat = nullptr;
    float* ref;
    bf16* hiddenF = nullptr;
    bool FULLH = false;
    if (FAST) {
        char* p = (char*)xb + MS * 2;
        W1t = (bf16*)p;   p += (size_t)2048 * 256 * 2;
        W2t = (bf16*)p;   p += (size_t)2048 * 256 * 2;
        Wvt = (bf16*)p;   p += (size_t)256 * 256 * 2;
        Wofft = (bf16*)p; p += (size_t)256 * 256 * 2;
        Wot = (bf16*)p;   p += (size_t)256 * 256 * 2;
        Wat = (bf16*)p;   p += (size_t)128 * 256 * 2;
        ref = (float*)p;  p += (size_t)S_TOT * 2 * 4;
        size_t used = (size_t)(p - (char*)d_ws);
        used = (used + 255) & ~(size_t)255;
        if (ws_size >= used + (size_t)BM * 2048 * 2) {
            hiddenF = (bf16*)((char*)d_ws + used);
            FULLH = true;
        }
    } else {
        ref = (float*)base;
    }

    bf16* hidden = FULLH ? hiddenF : value;
    const int CH = FULLH ? BM : 2816;

    detect_dtype<<<1, 256, 0, stream>>>((const unsigned short*)d_in[0], flag);

    {
        int HW0 = 76 * 76, HW1 = 38 * 38, HW2 = 19 * 19;
        int n0 = BATCH * HW0 * 256, n1 = BATCH * HW1 * 256, n2 = BATCH * HW2 * 256;
        pack_level<<<(n0 + 255) / 256, 256, 0, stream>>>(d_in[0], d_in[1], d_in[8], 0, x, pos, HW0, 0, flag);
        pack_level<<<(n1 + 255) / 256, 256, 0, stream>>>(d_in[2], d_in[3], d_in[8], 1, x, pos, HW1, 5776, flag);
        pack_level<<<(n2 + 255) / 256, 256, 0, stream>>>(d_in[4], d_in[5], d_in[8], 2, x, pos, HW2, 7220, flag);
        int nt = BATCH * 20 * 256;
        pack_task<<<(nt + 255) / 256, 256, 0, stream>>>(d_in[6], d_in[7], x, pos, flag);
        make_ref<<<(S_TOT + 255) / 256, 256, 0, stream>>>(ref);
    }

    const int GM = (BM + 127) / 128;      // 119
    const int GR4 = (BM + 3) / 4;         // 3801
    const int n4 = (int)(MS / 4);

    if (FAST) cvt_x<<<(n4 + 255) / 256, 256, 0, stream>>>(x, xb, n4);

    for (int L = 0; L < 6; ++L) {
        size_t oW256 = (size_t)L * 256 * 256, ob256 = (size_t)L * 256;
        size_t oW128 = (size_t)L * 256 * 128, ob128 = (size_t)L * 128;
        size_t oW1   = (size_t)L * 256 * 2048, ob1  = (size_t)L * 2048;
        size_t oW2   = (size_t)L * 2048 * 256;

        if (FAST) {
            dim3 t256(8, 8), t128a(4, 8), tW1(64, 8), tW2(8, 64);
            transpose_w<<<t256, 256, 0, stream>>>(d_in[13], oW256, Wvt, 256, 256, flag);
            transpose_w<<<t256, 256, 0, stream>>>(d_in[9],  oW256, Wofft, 256, 256, flag);
            transpose_w<<<t128a, 256, 0, stream>>>(d_in[11], oW128, Wat, 256, 128, flag);
            transpose_w<<<t256, 256, 0, stream>>>(d_in[15], oW256, Wot, 256, 256, flag);
            transpose_w<<<tW1, 256, 0, stream>>>(d_in[17], oW1, W1t, 256, 2048, flag);
            transpose_w<<<tW2, 256, 0, stream>>>(d_in[19], oW2, W2t, 2048, 256, flag);

            bf16* qb = yb;
            cvt_q<<<(n4 + 255) / 256, 256, 0, stream>>>(x, pos, qb, n4);

            mfma_gemm<<<dim3(2, GM), 256, 0, stream>>>(xb, Wvt, d_in[14], ob256, value, BM, 256, 256, 0, flag);
            mfma_gemm<<<dim3(2, GM), 256, 0, stream>>>(qb, Wofft, d_in[10], ob256, offms, BM, 256, 256, 0, flag);
            mfma_gemm<<<dim3(1, GM), 256, 0, stream>>>(qb, Wat, d_in[12], ob128, attnl, BM, 128, 256, 0, flag);

            msdeform_sample4<<<GR4, 256, 0, stream>>>(value, offms, attnl, ref, offms);

            mfma_gemm<<<dim3(2, GM), 256, 0, stream>>>(offms, Wot, d_in[16], ob256, yb, BM, 256, 256, 0, flag);
            residual_ln4<<<GR4, 256, 0, stream>>>(x, yb, d_in[21], ob256, d_in[22], ob256, flag, xb);

            for (int r0 = 0; r0 < BM; r0 += CH) {
                int mc = BM - r0 < CH ? BM - r0 : CH;
                int gmc = (mc + 127) / 128;
                mfma_gemm<<<dim3(16, gmc), 256, 0, stream>>>(xb + (size_t)r0 * 256, W1t, d_in[18], ob1,
                                                             hidden, mc, 2048, 256, 1, flag);
                mfma_gemm<<<dim3(2, gmc), 256, 0, stream>>>(hidden, W2t, d_in[20], ob256,
                                                            yb + (size_t)r0 * 256, mc, 256, 2048, 0, flag);
            }
            residual_ln4<<<GR4, 256, 0, stream>>>(x, yb, d_in[23], ob256, d_in[24], ob256, flag, xb);
        } else {
            dim3 g256(4, (BM + 63) / 64);
            dim3 g128(2, (BM + 63) / 64);
            gemm_bias<float, 0, 0><<<g256, 256, 0, stream>>>(x, nullptr, d_in[13], oW256, d_in[14], ob256,
                                                             value, BM, 256, 256, flag);
            gemm_bias<float, 1, 0><<<g256, 256, 0, stream>>>(x, pos, d_in[9], oW256, d_in[10], ob256,
                                                             offms, BM, 256, 256, flag);
            gemm_bias<float, 1, 0><<<g128, 256, 0, stream>>>(x, pos, d_in[11], oW128, d_in[12], ob128,
                                                             attnl, BM, 128, 256, flag);
            msdeform_sample4<<<GR4, 256, 0, stream>>>(value, offms, attnl, ref, offms);
            gemm_bias<bf16, 0, 0><<<g256, 256, 0, stream>>>(offms, nullptr, d_in[15], oW256, d_in[16], ob256,
                                                            yb, BM, 256, 256, flag);
            residual_ln4<<<GR4, 256, 0, stream>>>(x, yb, d_in[21], ob256, d_in[22], ob256, flag, nullptr);
            for (int r0 = 0; r0 < BM; r0 += CH) {
                int mc = BM - r0 < CH ? BM - r0 : CH;
                dim3 gh(32, (mc + 63) / 64);
                dim3 go(4, (mc + 63) / 64);
                gemm_bias<float, 0, 1><<<gh, 256, 0, stream>>>(x + (size_t)r0 * 256, nullptr, d_in[17], oW1,
                                                               d_in[18], ob1, hidden, mc, 2048, 256, flag);
                gemm_bias<bf16, 0, 0><<<go, 256, 0, stream>>>(hidden, nullptr, d_in[19], oW2, d_in[20], ob256,
                                                              yb + (size_t)r0 * 256, mc, 256, 2048, flag);
            }
            residual_ln4<<<GR4, 256, 0, stream>>>(x, yb, d_in[23], ob256, d_in[24], ob256, flag, nullptr);
        }
    }

    cast_out<<<((int)MS + 255) / 256, 256, 0, stream>>>(x, d_out, (int)MS, flag);
}

// Round 7
// 1543.937 us; speedup vs baseline: 9.9226x; 1.2193x over previous
//
#include <hip/hip_runtime.h>

#define S_TOT 7601
#define BATCH 2
#define BM (BATCH * S_TOT)   // 15202
#define DMODEL 256

typedef unsigned short bf16;
typedef __attribute__((ext_vector_type(8))) short v8s;
typedef __attribute__((ext_vector_type(4))) float v4f;

__device__ __forceinline__ float b2f(bf16 u) {
    union { unsigned int i; float f; } v;
    v.i = ((unsigned int)u) << 16;
    return v.f;
}
__device__ __forceinline__ bf16 f2b(float f) {
    union { unsigned int i; float f; } v;
    v.f = f;
    unsigned int r = v.i + 0x7FFFu + ((v.i >> 16) & 1u);
    return (bf16)(r >> 16);
}
__device__ __forceinline__ float ldin(const void* p, size_t i, int isf32) {
    return isf32 ? ((const float*)p)[i] : b2f(((const bf16*)p)[i]);
}

// ---------------- dtype probe ----------------
__global__ void detect_dtype(const unsigned short* __restrict__ src, int* __restrict__ flag) {
    __shared__ int cnt;
    if (threadIdx.x == 0) cnt = 0;
    __syncthreads();
    int local = 0;
    for (int i = threadIdx.x; i < 16384; i += 256) {
        unsigned int e = (src[i] >> 7) & 0xFFu;
        if (e >= 143u) local++;
    }
    atomicAdd(&cnt, local);
    __syncthreads();
    if (threadIdx.x == 0) *flag = (cnt > 200) ? 1 : 0;
}

// ---------------- pack ----------------
__global__ void __launch_bounds__(256) pack_level(const void* __restrict__ src,
                                                  const void* __restrict__ pin,
                                                  const void* __restrict__ lemb, int lrow,
                                                  float* __restrict__ x,
                                                  bf16* __restrict__ pout,
                                                  int HW, int start,
                                                  const int* __restrict__ flag) {
    int isf32 = *flag;
    int i = blockIdx.x * 256 + threadIdx.x;
    int total = BATCH * HW * 256;
    if (i >= total) return;
    int c = i & 255;
    int t = i >> 8;
    int s = t % HW;
    int b = t / HW;
    size_t src_idx = ((size_t)b * 256 + c) * HW + s;
    float sv = ldin(src, src_idx, isf32);
    float pv = ldin(pin, src_idx, isf32) + ldin(lemb, (size_t)lrow * 256 + c, isf32);
    size_t o = ((size_t)b * S_TOT + start + s) * 256 + c;
    x[o] = sv;
    pout[o] = f2b(pv);
}

__global__ void __launch_bounds__(256) pack_task(const void* __restrict__ te,
                                                 const void* __restrict__ tpe,
                                                 float* __restrict__ x,
                                                 bf16* __restrict__ pout,
                                                 const int* __restrict__ flag) {
    int isf32 = *flag;
    int i = blockIdx.x * 256 + threadIdx.x;
    int total = BATCH * 20 * 256;
    if (i >= total) return;
    int c = i & 255;
    int t = (i >> 8) % 20;
    int b = (i >> 8) / 20;
    size_t o = ((size_t)b * S_TOT + 7581 + t) * 256 + c;
    x[o] = ldin(te, ((size_t)b * 20 + t) * 256 + c, isf32);
    pout[o] = f2b(ldin(tpe, (size_t)t * 256 + c, isf32));
}

__global__ void __launch_bounds__(256) make_ref(float* __restrict__ ref) {
    int s = blockIdx.x * 256 + threadIdx.x;
    if (s >= S_TOT) return;
    int H, W, st;
    if (s < 5776)      { H = 76; W = 76; st = 0; }
    else if (s < 7220) { H = 38; W = 38; st = 5776; }
    else if (s < 7581) { H = 19; W = 19; st = 7220; }
    else               { H = 1;  W = 20; st = 7581; }
    int r = s - st;
    int i = r / W, j = r % W;
    ref[s * 2 + 0] = (j + 0.5f) / (float)W;
    ref[s * 2 + 1] = (i + 0.5f) / (float)H;
}

__global__ void __launch_bounds__(256) cast_out(const float* __restrict__ x,
                                                void* __restrict__ o, int n,
                                                const int* __restrict__ flag) {
    int isf32 = *flag;
    int i = blockIdx.x * 256 + threadIdx.x;
    if (i >= n) return;
    if (isf32) ((float*)o)[i] = x[i];
    else       ((bf16*)o)[i] = f2b(x[i]);
}

// ---------------- cvt: xb = bf16(x) ----------------
__global__ void __launch_bounds__(256) cvt_x(const float* __restrict__ x,
                                             bf16* __restrict__ xb, int n4) {
    int i = blockIdx.x * 256 + threadIdx.x;
    if (i >= n4) return;
    float4 xv = ((const float4*)x)[i];
    ushort4 xo;
    xo.x = f2b(xv.x); xo.y = f2b(xv.y); xo.z = f2b(xv.z); xo.w = f2b(xv.w);
    ((ushort4*)xb)[i] = xo;
}

// ---------------- cvt: qb = bf16(x + pos) ----------------
__global__ void __launch_bounds__(256) cvt_q(const float* __restrict__ x,
                                             const bf16* __restrict__ pos,
                                             bf16* __restrict__ qb, int n4) {
    int i = blockIdx.x * 256 + threadIdx.x;
    if (i >= n4) return;
    float4 xv = ((const float4*)x)[i];
    ushort4 pv = ((const ushort4*)pos)[i];
    ushort4 qo;
    qo.x = f2b(xv.x + b2f(pv.x));
    qo.y = f2b(xv.y + b2f(pv.y));
    qo.z = f2b(xv.z + b2f(pv.z));
    qo.w = f2b(xv.w + b2f(pv.w));
    ((ushort4*)qb)[i] = qo;
}

// ---------------- all-weights transpose for one layer: 1248 tiles of 32x32 ----------------
__global__ void __launch_bounds__(256) transpose_all(const void* __restrict__ Wv,
                                                     const void* __restrict__ Woff,
                                                     const void* __restrict__ Wa,
                                                     const void* __restrict__ Wo,
                                                     const void* __restrict__ W1,
                                                     const void* __restrict__ W2,
                                                     bf16* __restrict__ Wvt,
                                                     bf16* __restrict__ Wofft,
                                                     bf16* __restrict__ Wat,
                                                     bf16* __restrict__ Wot,
                                                     bf16* __restrict__ W1t,
                                                     bf16* __restrict__ W2t,
                                                     int L, const int* __restrict__ flag) {
    int isf32 = *flag;
    int t = blockIdx.x;
    const void* src; bf16* dst; int K, N; size_t woff;
    if (t < 64)        { src = Wv;   dst = Wvt;   K = 256;  N = 256;  woff = (size_t)L * 65536; }
    else if (t < 128)  { src = Woff; dst = Wofft; K = 256;  N = 256;  woff = (size_t)L * 65536;  t -= 64; }
    else if (t < 160)  { src = Wa;   dst = Wat;   K = 256;  N = 128;  woff = (size_t)L * 32768;  t -= 128; }
    else if (t < 224)  { src = Wo;   dst = Wot;   K = 256;  N = 256;  woff = (size_t)L * 65536;  t -= 160; }
    else if (t < 736)  { src = W1;   dst = W1t;   K = 256;  N = 2048; woff = (size_t)L * 524288; t -= 224; }
    else               { src = W2;   dst = W2t;   K = 2048; N = 256;  woff = (size_t)L * 524288; t -= 736; }
    int ntx = N >> 5;
    int tk = (t / ntx) * 32;
    int tn = (t % ntx) * 32;
    __shared__ float tl[32][33];
    int r = threadIdx.x >> 3;
    int c4 = (threadIdx.x & 7) * 4;
#pragma unroll
    for (int i = 0; i < 4; ++i)
        tl[r][c4 + i] = ldin(src, woff + (size_t)(tk + r) * N + tn + c4 + i, isf32);
    __syncthreads();
#pragma unroll
    for (int i = 0; i < 4; ++i)
        dst[(size_t)(tn + r) * K + tk + c4 + i] = f2b(tl[c4 + i][r]);
}

// ---------------- MFMA GEMM 128x128 (for large-N: FFN1) ----------------
__global__ void __launch_bounds__(256) mfma_gemm(const bf16* __restrict__ A,
                                                 const bf16* __restrict__ Wt,
                                                 const void* __restrict__ bias, size_t boff,
                                                 bf16* __restrict__ C,
                                                 int M, int N, int K, int relu,
                                                 const int* __restrict__ flag) {
    int isf32 = *flag;
    __shared__ __align__(16) bf16 As[128 * 40];
    __shared__ __align__(16) bf16 Bs[128 * 40];
    int tid = threadIdx.x;
    int lane = tid & 63, wave = tid >> 6;
    int wm = (wave & 1) << 6, wn = (wave >> 1) << 6;
    int bm = blockIdx.y * 128, bn = blockIdx.x * 128;
    int q = lane >> 4, l15 = lane & 15;

    v4f acc[4][4];
#pragma unroll
    for (int i = 0; i < 4; ++i)
#pragma unroll
        for (int j = 0; j < 4; ++j) acc[i][j] = (v4f){0.f, 0.f, 0.f, 0.f};

    int ar = tid >> 2;
    int ak = (tid & 3) * 8;
    int brow = tid >> 1;
    int bkh = (tid & 1) * 16;

    for (int k0 = 0; k0 < K; k0 += 32) {
#pragma unroll
        for (int h = 0; h < 2; ++h) {
            int row = ar + 64 * h;
            int gm = bm + row;
            uint4 av = make_uint4(0, 0, 0, 0);
            if (gm < M) av = *(const uint4*)(A + (size_t)gm * K + k0 + ak);
            *(uint4*)&As[row * 40 + ak] = av;
        }
        {
            const bf16* wrow = Wt + (size_t)(bn + brow) * K + k0 + bkh;
            uint4 w0 = *(const uint4*)wrow;
            uint4 w1 = *(const uint4*)(wrow + 8);
            *(uint4*)&Bs[brow * 40 + bkh] = w0;
            *(uint4*)&Bs[brow * 40 + bkh + 8] = w1;
        }
        __syncthreads();
        v8s a_frag[4], b_frag[4];
#pragma unroll
        for (int mi = 0; mi < 4; ++mi)
            a_frag[mi] = *(const v8s*)&As[(wm + mi * 16 + l15) * 40 + q * 8];
#pragma unroll
        for (int ni = 0; ni < 4; ++ni)
            b_frag[ni] = *(const v8s*)&Bs[(wn + ni * 16 + l15) * 40 + q * 8];
#pragma unroll
        for (int mi = 0; mi < 4; ++mi)
#pragma unroll
            for (int ni = 0; ni < 4; ++ni)
                acc[mi][ni] = __builtin_amdgcn_mfma_f32_16x16x32_bf16(
                    a_frag[mi], b_frag[ni], acc[mi][ni], 0, 0, 0);
        __syncthreads();
    }

#pragma unroll
    for (int ni = 0; ni < 4; ++ni) {
        int gn = bn + wn + ni * 16 + l15;
        float bv = ldin(bias, boff + gn, isf32);
#pragma unroll
        for (int mi = 0; mi < 4; ++mi) {
#pragma unroll
            for (int r = 0; r < 4; ++r) {
                int gm = bm + wm + mi * 16 + q * 4 + r;
                if (gm < M) {
                    float v = acc[mi][ni][r] + bv;
                    if (relu) v = fmaxf(v, 0.f);
                    C[(size_t)gm * N + gn] = f2b(v);
                }
            }
        }
    }
}

// ---------------- MFMA GEMM 64x64 (for small-N: high block count / occupancy) ----------------
__global__ void __launch_bounds__(256) mfma_gemm64(const bf16* __restrict__ A,
                                                   const bf16* __restrict__ Wt,
                                                   const void* __restrict__ bias, size_t boff,
                                                   bf16* __restrict__ C,
                                                   int M, int N, int K, int relu,
                                                   const int* __restrict__ flag) {
    int isf32 = *flag;
    __shared__ __align__(16) bf16 As[64 * 40];
    __shared__ __align__(16) bf16 Bs[64 * 40];
    int tid = threadIdx.x;
    int lane = tid & 63, wave = tid >> 6;
    int wm = (wave & 1) * 32, wn = (wave >> 1) * 32;
    int bm = blockIdx.y * 64, bn = blockIdx.x * 64;
    int q = lane >> 4, l15 = lane & 15;

    v4f acc[2][2];
#pragma unroll
    for (int i = 0; i < 2; ++i)
#pragma unroll
        for (int j = 0; j < 2; ++j) acc[i][j] = (v4f){0.f, 0.f, 0.f, 0.f};

    int srow = tid >> 2;          // 0..63
    int sk = (tid & 3) * 8;       // 0,8,16,24
    bool aok = (bm + srow) < M;
    const bf16* arow = A + (size_t)(aok ? (bm + srow) : 0) * K;
    const bf16* brow = Wt + (size_t)(bn + srow) * K;

    for (int k0 = 0; k0 < K; k0 += 32) {
        uint4 av = make_uint4(0, 0, 0, 0);
        if (aok) av = *(const uint4*)(arow + k0 + sk);
        uint4 bv = *(const uint4*)(brow + k0 + sk);
        *(uint4*)&As[srow * 40 + sk] = av;
        *(uint4*)&Bs[srow * 40 + sk] = bv;
        __syncthreads();
        v8s a_frag[2], b_frag[2];
#pragma unroll
        for (int mi = 0; mi < 2; ++mi)
            a_frag[mi] = *(const v8s*)&As[(wm + mi * 16 + l15) * 40 + q * 8];
#pragma unroll
        for (int ni = 0; ni < 2; ++ni)
            b_frag[ni] = *(const v8s*)&Bs[(wn + ni * 16 + l15) * 40 + q * 8];
#pragma unroll
        for (int mi = 0; mi < 2; ++mi)
#pragma unroll
            for (int ni = 0; ni < 2; ++ni)
                acc[mi][ni] = __builtin_amdgcn_mfma_f32_16x16x32_bf16(
                    a_frag[mi], b_frag[ni], acc[mi][ni], 0, 0, 0);
        __syncthreads();
    }

#pragma unroll
    for (int ni = 0; ni < 2; ++ni) {
        int gn = bn + wn + ni * 16 + l15;
        float bv = ldin(bias, boff + gn, isf32);
#pragma unroll
        for (int mi = 0; mi < 2; ++mi) {
#pragma unroll
            for (int r = 0; r < 4; ++r) {
                int gm = bm + wm + mi * 16 + q * 4 + r;
                if (gm < M) {
                    float v = acc[mi][ni][r] + bv;
                    if (relu) v = fmaxf(v, 0.f);
                    C[(size_t)gm * N + gn] = f2b(v);
                }
            }
        }
    }
}

// ---------------- fallback VALU GEMM ----------------
template<typename TA, int ADDPOS, int RELU>
__global__ void __launch_bounds__(256) gemm_bias(const TA* __restrict__ A,
                                                 const bf16* __restrict__ Apos,
                                                 const void* __restrict__ W, size_t woff,
                                                 const void* __restrict__ bias, size_t boff,
                                                 bf16* __restrict__ C,
                                                 int M, int N, int K,
                                                 const int* __restrict__ flag) {
    int isf32 = *flag;
    __shared__ float As[16][65];
    __shared__ float Bs[16][65];
    int tid = threadIdx.x;
    int tx = tid & 15;
    int ty = tid >> 4;
    int bm = blockIdx.y * 64;
    int bn = blockIdx.x * 64;
    float acc[4][4] = {};
    for (int k0 = 0; k0 < K; k0 += 16) {
#pragma unroll
        for (int e = 0; e < 4; ++e) {
            int idx = tid + e * 256;
            int mm = idx >> 4;
            int kk = idx & 15;
            int gm = bm + mm;
            float av = 0.f;
            if (gm < M) {
                size_t ai = (size_t)gm * K + k0 + kk;
                if (sizeof(TA) == 4) av = ((const float*)A)[ai];
                else                 av = b2f(((const bf16*)A)[ai]);
                if (ADDPOS) av += b2f(Apos[ai]);
            }
            As[kk][mm] = av;
        }
#pragma unroll
        for (int e = 0; e < 4; ++e) {
            int idx = tid + e * 256;
            int kk = idx >> 6;
            int nn = idx & 63;
            int gn = bn + nn;
            Bs[kk][nn] = (gn < N) ? ldin(W, woff + (size_t)(k0 + kk) * N + gn, isf32) : 0.f;
        }
        __syncthreads();
#pragma unroll
        for (int kk = 0; kk < 16; ++kk) {
            float a[4], b[4];
#pragma unroll
            for (int i = 0; i < 4; ++i) a[i] = As[kk][ty + 16 * i];
#pragma unroll
            for (int j = 0; j < 4; ++j) b[j] = Bs[kk][tx + 16 * j];
#pragma unroll
            for (int i = 0; i < 4; ++i)
#pragma unroll
                for (int j = 0; j < 4; ++j) acc[i][j] += a[i] * b[j];
        }
        __syncthreads();
    }
#pragma unroll
    for (int i = 0; i < 4; ++i) {
        int gm = bm + ty + 16 * i;
        if (gm >= M) continue;
#pragma unroll
        for (int j = 0; j < 4; ++j) {
            int gn = bn + tx + 16 * j;
            if (gn >= N) continue;
            float v = acc[i][j] + ldin(bias, boff + gn, isf32);
            if (RELU) v = fmaxf(v, 0.f);
            C[(size_t)gm * N + gn] = f2b(v);
        }
    }
}

// ---------------- MS-deform sampling: 4 rows/block, corner descriptors in LDS ----------------
__global__ void __launch_bounds__(256) msdeform_sample4(const bf16* __restrict__ value,
                                                        const bf16* __restrict__ off,
                                                        const bf16* __restrict__ logits,
                                                        const float* __restrict__ refpts,
                                                        bf16* __restrict__ out) {
    __shared__ float sAttn[4 * 128];
    __shared__ int2 sIW[4 * 520];
    const int LH[4] = {76, 38, 19, 1};
    const int LW[4] = {76, 38, 19, 20};
    const int LS[4] = {0, 5776, 7220, 7581};
    int tid = threadIdx.x;
    int m0 = blockIdx.x * 4;

    for (int i = tid; i < 4 * 128; i += 256) {
        int r = i >> 7, li = i & 127;
        int m = m0 + r;
        int mc = (m < BM) ? m : BM - 1;
        sAttn[i] = b2f(logits[(size_t)mc * 128 + li]);
    }
    __syncthreads();
    if (tid < 32) {
        float* g = sAttn + tid * 16;
        float mx = -1e30f;
#pragma unroll
        for (int i = 0; i < 16; ++i) mx = fmaxf(mx, g[i]);
        float e[16], sm = 0.f;
#pragma unroll
        for (int i = 0; i < 16; ++i) { e[i] = __expf(g[i] - mx); sm += e[i]; }
        float inv = 1.f / sm;
#pragma unroll
        for (int i = 0; i < 16; ++i) g[i] = e[i] * inv;
    }
    __syncthreads();
    for (int i = tid; i < 4 * 128; i += 256) {
        int r = i >> 7, oi = i & 127;
        int m = m0 + r;
        int mc = (m < BM) ? m : BM - 1;
        int b = mc / S_TOT;
        int s = mc - b * S_TOT;
        int h = oi >> 4;
        int l = (oi >> 2) & 3;
        int H = LH[l], W = LW[l], st = LS[l];
        float fW = (float)W, fH = (float)H;
        float refx = refpts[s * 2 + 0];
        float refy = refpts[s * 2 + 1];
        ushort2 ov = *(const ushort2*)(off + (size_t)mc * 256 + oi * 2);
        float a = sAttn[r * 128 + oi];
        float xpix = (refx + b2f(ov.x) / fW) * fW - 0.5f;
        float ypix = (refy + b2f(ov.y) / fH) * fH - 0.5f;
        float x0f = floorf(xpix), y0f = floorf(ypix);
        int x0 = (int)x0f, y0 = (int)y0f;
        float wx1 = xpix - x0f, wy1 = ypix - y0f;
        float wx0 = 1.f - wx1, wy0 = 1.f - wy1;
        int vb = b * (S_TOT * 256) + h * 32;
        int base = r * 520 + h * 65 + (oi & 15) * 4;
#pragma unroll
        for (int c = 0; c < 4; ++c) {
            int cx = c & 1, cy = c >> 1;
            int xi = x0 + cx, yi = y0 + cy;
            float w = (cx ? wx1 : wx0) * (cy ? wy1 : wy0) * a;
            bool valid = (xi >= 0) && (xi <= W - 1) && (yi >= 0) && (yi <= H - 1);
            int xic = min(max(xi, 0), W - 1), yic = min(max(yi, 0), H - 1);
            int2 d;
            d.x = vb + (st + yic * W + xic) * 256;
            d.y = __float_as_int(valid ? w : 0.f);
            sIW[base + c] = d;
        }
    }
    __syncthreads();
    int r = tid >> 6, u = tid & 63;
    int h = u >> 3, d4 = (u & 7) * 4;
    int m = m0 + r;
    int cb = r * 520 + h * 65;
    float acc0 = 0.f, acc1 = 0.f, acc2 = 0.f, acc3 = 0.f;
#pragma unroll 8
    for (int c = 0; c < 64; ++c) {
        int2 p = sIW[cb + c];
        float w = __int_as_float(p.y);
        ushort4 v = *(const ushort4*)(value + p.x + d4);
        acc0 += w * b2f(v.x);
        acc1 += w * b2f(v.y);
        acc2 += w * b2f(v.z);
        acc3 += w * b2f(v.w);
    }
    if (m < BM) {
        ushort4 o;
        o.x = f2b(acc0); o.y = f2b(acc1); o.z = f2b(acc2); o.w = f2b(acc3);
        *(ushort4*)(out + (size_t)m * 256 + h * 32 + d4) = o;
    }
}

// ---------------- residual + LayerNorm: 4 rows/block, 1 wave/row; optional xb and qb=bf16(x+pos) ----------------
__global__ void __launch_bounds__(256) residual_ln4(float* __restrict__ x,
                                                    const bf16* __restrict__ y,
                                                    const void* __restrict__ g, size_t goff,
                                                    const void* __restrict__ beta, size_t boff,
                                                    const int* __restrict__ flag,
                                                    bf16* __restrict__ xb,
                                                    const bf16* __restrict__ pos,
                                                    bf16* __restrict__ qb) {
    int isf32 = *flag;
    int tid = threadIdx.x;
    int r = tid >> 6, lane = tid & 63;
    int m = blockIdx.x * 4 + r;
    if (m >= BM) return;
    size_t o = (size_t)m * 256 + lane * 4;
    float4 xv = *(const float4*)(x + o);
    ushort4 yv = *(const ushort4*)(y + o);
    float r0 = xv.x + b2f(yv.x), r1 = xv.y + b2f(yv.y);
    float r2 = xv.z + b2f(yv.z), r3 = xv.w + b2f(yv.w);
    float sum = r0 + r1 + r2 + r3;
#pragma unroll
    for (int ofs = 32; ofs > 0; ofs >>= 1) sum += __shfl_xor(sum, ofs);
    float mean = sum * (1.f / 256.f);
    float d0 = r0 - mean, d1 = r1 - mean, d2 = r2 - mean, d3 = r3 - mean;
    float vv = d0 * d0 + d1 * d1 + d2 * d2 + d3 * d3;
#pragma unroll
    for (int ofs = 32; ofs > 0; ofs >>= 1) vv += __shfl_xor(vv, ofs);
    float rstd = rsqrtf(vv * (1.f / 256.f) + 1e-5f);
    int c = lane * 4;
    float o0 = d0 * rstd * ldin(g, goff + c + 0, isf32) + ldin(beta, boff + c + 0, isf32);
    float o1 = d1 * rstd * ldin(g, goff + c + 1, isf32) + ldin(beta, boff + c + 1, isf32);
    float o2 = d2 * rstd * ldin(g, goff + c + 2, isf32) + ldin(beta, boff + c + 2, isf32);
    float o3 = d3 * rstd * ldin(g, goff + c + 3, isf32) + ldin(beta, boff + c + 3, isf32);
    *(float4*)(x + o) = make_float4(o0, o1, o2, o3);
    if (xb) {
        ushort4 xo;
        xo.x = f2b(o0); xo.y = f2b(o1); xo.z = f2b(o2); xo.w = f2b(o3);
        *(ushort4*)(xb + o) = xo;
    }
    if (qb) {
        ushort4 pv = *(const ushort4*)(pos + o);
        ushort4 qo;
        qo.x = f2b(o0 + b2f(pv.x));
        qo.y = f2b(o1 + b2f(pv.y));
        qo.z = f2b(o2 + b2f(pv.z));
        qo.w = f2b(o3 + b2f(pv.w));
        *(ushort4*)(qb + o) = qo;
    }
}

// ---------------- host ----------------
extern "C" void kernel_launch(void* const* d_in, const int* in_sizes, int n_in,
                              void* d_out, int out_size, void* d_ws, size_t ws_size,
                              hipStream_t stream) {
    (void)in_sizes; (void)n_in; (void)out_size;
    const size_t MS = (size_t)BM * DMODEL;   // 3,891,712

    char* base = (char*)d_ws;
    int* flag    = (int*)base;    base += 256;
    float* x     = (float*)base;  base += MS * 4;
    bf16* value  = (bf16*)base;   base += MS * 2;
    bf16* attnl  = (bf16*)base;   base += (size_t)BM * 128 * 2;
    bf16* pos    = (bf16*)base;   base += MS * 2;
    bf16* offms  = (bf16*)base;   base += MS * 2;   // off -> msout in place
    bf16* yb     = (bf16*)base;   base += MS * 2;   // also qb (dead before Wo writes)
    size_t base_used = (size_t)(base - (char*)d_ws);

    bf16* xb = (bf16*)base;
    size_t need_fast = base_used + MS * 2
                     + (size_t)2048 * 256 * 2 * 2
                     + (size_t)256 * 256 * 2 * 3
                     + (size_t)128 * 256 * 2
                     + (size_t)S_TOT * 2 * 4 + 1024;
    bool FAST = ws_size >= need_fast;

    bf16 *W1t = nullptr, *W2t = nullptr, *Wvt = nullptr, *Wofft = nullptr, *Wot = nullptr, *Wat = nullptr;
    float* ref;
    bf16* hiddenF = nullptr;
    bool FULLH = false;
    if (FAST) {
        char* p = (char*)xb + MS * 2;
        W1t = (bf16*)p;   p += (size_t)2048 * 256 * 2;
        W2t = (bf16*)p;   p += (size_t)2048 * 256 * 2;
        Wvt = (bf16*)p;   p += (size_t)256 * 256 * 2;
        Wofft = (bf16*)p; p += (size_t)256 * 256 * 2;
        Wot = (bf16*)p;   p += (size_t)256 * 256 * 2;
        Wat = (bf16*)p;   p += (size_t)128 * 256 * 2;
        ref = (float*)p;  p += (size_t)S_TOT * 2 * 4;
        size_t used = (size_t)(p - (char*)d_ws);
        used = (used + 255) & ~(size_t)255;
        if (ws_size >= used + (size_t)BM * 2048 * 2) {
            hiddenF = (bf16*)((char*)d_ws + used);
            FULLH = true;
        }
    } else {
        ref = (float*)base;
    }

    bf16* hidden = FULLH ? hiddenF : value;
    const int CH = FULLH ? BM : 2816;

    detect_dtype<<<1, 256, 0, stream>>>((const unsigned short*)d_in[0], flag);

    {
        int HW0 = 76 * 76, HW1 = 38 * 38, HW2 = 19 * 19;
        int n0 = BATCH * HW0 * 256, n1 = BATCH * HW1 * 256, n2 = BATCH * HW2 * 256;
        pack_level<<<(n0 + 255) / 256, 256, 0, stream>>>(d_in[0], d_in[1], d_in[8], 0, x, pos, HW0, 0, flag);
        pack_level<<<(n1 + 255) / 256, 256, 0, stream>>>(d_in[2], d_in[3], d_in[8], 1, x, pos, HW1, 5776, flag);
        pack_level<<<(n2 + 255) / 256, 256, 0, stream>>>(d_in[4], d_in[5], d_in[8], 2, x, pos, HW2, 7220, flag);
        int nt = BATCH * 20 * 256;
        pack_task<<<(nt + 255) / 256, 256, 0, stream>>>(d_in[6], d_in[7], x, pos, flag);
        make_ref<<<(S_TOT + 255) / 256, 256, 0, stream>>>(ref);
    }

    const int GM64 = (BM + 63) / 64;      // 238
    const int GM128 = (BM + 127) / 128;   // 119
    const int GR4 = (BM + 3) / 4;         // 3801
    const int n4 = (int)(MS / 4);

    if (FAST) {
        cvt_x<<<(n4 + 255) / 256, 256, 0, stream>>>(x, xb, n4);
        cvt_q<<<(n4 + 255) / 256, 256, 0, stream>>>(x, pos, yb, n4);   // qb for layer 0
    }

    for (int L = 0; L < 6; ++L) {
        size_t oW256 = (size_t)L * 256 * 256, ob256 = (size_t)L * 256;
        size_t oW128 = (size_t)L * 256 * 128, ob128 = (size_t)L * 128;
        size_t oW1   = (size_t)L * 256 * 2048, ob1  = (size_t)L * 2048;
        size_t oW2   = (size_t)L * 2048 * 256;

        if (FAST) {
            transpose_all<<<1248, 256, 0, stream>>>(d_in[13], d_in[9], d_in[11], d_in[15], d_in[17], d_in[19],
                                                    Wvt, Wofft, Wat, Wot, W1t, W2t, L, flag);
            bf16* qb = yb;
            mfma_gemm64<<<dim3(4, GM64), 256, 0, stream>>>(xb, Wvt, d_in[14], ob256, value, BM, 256, 256, 0, flag);
            mfma_gemm64<<<dim3(4, GM64), 256, 0, stream>>>(qb, Wofft, d_in[10], ob256, offms, BM, 256, 256, 0, flag);
            mfma_gemm64<<<dim3(2, GM64), 256, 0, stream>>>(qb, Wat, d_in[12], ob128, attnl, BM, 128, 256, 0, flag);

            msdeform_sample4<<<GR4, 256, 0, stream>>>(value, offms, attnl, ref, offms);

            mfma_gemm64<<<dim3(4, GM64), 256, 0, stream>>>(offms, Wot, d_in[16], ob256, yb, BM, 256, 256, 0, flag);
            residual_ln4<<<GR4, 256, 0, stream>>>(x, yb, d_in[21], ob256, d_in[22], ob256, flag, xb, nullptr, nullptr);

            for (int r0 = 0; r0 < BM; r0 += CH) {
                int mc = BM - r0 < CH ? BM - r0 : CH;
                int gmc128 = (mc + 127) / 128;
                int gmc64 = (mc + 63) / 64;
                mfma_gemm<<<dim3(16, gmc128), 256, 0, stream>>>(xb + (size_t)r0 * 256, W1t, d_in[18], ob1,
                                                                hidden, mc, 2048, 256, 1, flag);
                mfma_gemm64<<<dim3(4, gmc64), 256, 0, stream>>>(hidden, W2t, d_in[20], ob256,
                                                                yb + (size_t)r0 * 256, mc, 256, 2048, 0, flag);
            }
            // emits xb for next use and qb (= bf16(x+pos), into yb) for next layer's off/attn GEMMs
            residual_ln4<<<GR4, 256, 0, stream>>>(x, yb, d_in[23], ob256, d_in[24], ob256, flag, xb,
                                                  (L < 5) ? pos : nullptr, (L < 5) ? yb : nullptr);
        } else {
            dim3 g256(4, GM64);
            dim3 g128(2, GM64);
            gemm_bias<float, 0, 0><<<g256, 256, 0, stream>>>(x, nullptr, d_in[13], oW256, d_in[14], ob256,
                                                             value, BM, 256, 256, flag);
            gemm_bias<float, 1, 0><<<g256, 256, 0, stream>>>(x, pos, d_in[9], oW256, d_in[10], ob256,
                                                             offms, BM, 256, 256, flag);
            gemm_bias<float, 1, 0><<<g128, 256, 0, stream>>>(x, pos, d_in[11], oW128, d_in[12], ob128,
                                                             attnl, BM, 128, 256, flag);
            msdeform_sample4<<<GR4, 256, 0, stream>>>(value, offms, attnl, ref, offms);
            gemm_bias<bf16, 0, 0><<<g256, 256, 0, stream>>>(offms, nullptr, d_in[15], oW256, d_in[16], ob256,
                                                            yb, BM, 256, 256, flag);
            residual_ln4<<<GR4, 256, 0, stream>>>(x, yb, d_in[21], ob256, d_in[22], ob256, flag, nullptr, nullptr, nullptr);
            for (int r0 = 0; r0 < BM; r0 += CH) {
                int mc = BM - r0 < CH ? BM - r0 : CH;
                dim3 gh(32, (mc + 63) / 64);
                dim3 go(4, (mc + 63) / 64);
                gemm_bias<float, 0, 1><<<gh, 256, 0, stream>>>(x + (size_t)r0 * 256, nullptr, d_in[17], oW1,
                                                               d_in[18], ob1, hidden, mc, 2048, 256, flag);
                gemm_bias<bf16, 0, 0><<<go, 256, 0, stream>>>(hidden, nullptr, d_in[19], oW2, d_in[20], ob256,
                                                              yb + (size_t)r0 * 256, mc, 256, 2048, flag);
            }
            residual_ln4<<<GR4, 256, 0, stream>>>(x, yb, d_in[23], ob256, d_in[24], ob256, flag, nullptr, nullptr, nullptr);
        }
    }

    cast_out<<<((int)MS + 255) / 256, 256, 0, stream>>>(x, d_out, (int)MS, flag);
}

// Round 9
// 1453.339 us; speedup vs baseline: 10.5412x; 1.0623x over previous
//
#include <hip/hip_runtime.h>

#define S_TOT 7601
#define BATCH 2
#define BM (BATCH * S_TOT)   // 15202
#define DMODEL 256

typedef unsigned short bf16;
typedef __attribute__((ext_vector_type(8))) short v8s;
typedef __attribute__((ext_vector_type(4))) float v4f;

__device__ __forceinline__ float b2f(bf16 u) {
    union { unsigned int i; float f; } v;
    v.i = ((unsigned int)u) << 16;
    return v.f;
}
__device__ __forceinline__ bf16 f2b(float f) {
    union { unsigned int i; float f; } v;
    v.f = f;
    unsigned int r = v.i + 0x7FFFu + ((v.i >> 16) & 1u);
    return (bf16)(r >> 16);
}
__device__ __forceinline__ float ldin(const void* p, size_t i, int isf32) {
    return isf32 ? ((const float*)p)[i] : b2f(((const bf16*)p)[i]);
}

// ---------------- dtype probe ----------------
__global__ void detect_dtype(const unsigned short* __restrict__ src, int* __restrict__ flag) {
    __shared__ int cnt;
    if (threadIdx.x == 0) cnt = 0;
    __syncthreads();
    int local = 0;
    for (int i = threadIdx.x; i < 16384; i += 256) {
        unsigned int e = (src[i] >> 7) & 0xFFu;
        if (e >= 143u) local++;
    }
    atomicAdd(&cnt, local);
    __syncthreads();
    if (threadIdx.x == 0) *flag = (cnt > 200) ? 1 : 0;
}

// ---------------- pack ----------------
__global__ void __launch_bounds__(256) pack_level(const void* __restrict__ src,
                                                  const void* __restrict__ pin,
                                                  const void* __restrict__ lemb, int lrow,
                                                  float* __restrict__ x,
                                                  bf16* __restrict__ pout,
                                                  int HW, int start,
                                                  const int* __restrict__ flag) {
    int isf32 = *flag;
    int i = blockIdx.x * 256 + threadIdx.x;
    int total = BATCH * HW * 256;
    if (i >= total) return;
    int c = i & 255;
    int t = i >> 8;
    int s = t % HW;
    int b = t / HW;
    size_t src_idx = ((size_t)b * 256 + c) * HW + s;
    float sv = ldin(src, src_idx, isf32);
    float pv = ldin(pin, src_idx, isf32) + ldin(lemb, (size_t)lrow * 256 + c, isf32);
    size_t o = ((size_t)b * S_TOT + start + s) * 256 + c;
    x[o] = sv;
    pout[o] = f2b(pv);
}

__global__ void __launch_bounds__(256) pack_task(const void* __restrict__ te,
                                                 const void* __restrict__ tpe,
                                                 float* __restrict__ x,
                                                 bf16* __restrict__ pout,
                                                 const int* __restrict__ flag) {
    int isf32 = *flag;
    int i = blockIdx.x * 256 + threadIdx.x;
    int total = BATCH * 20 * 256;
    if (i >= total) return;
    int c = i & 255;
    int t = (i >> 8) % 20;
    int b = (i >> 8) / 20;
    size_t o = ((size_t)b * S_TOT + 7581 + t) * 256 + c;
    x[o] = ldin(te, ((size_t)b * 20 + t) * 256 + c, isf32);
    pout[o] = f2b(ldin(tpe, (size_t)t * 256 + c, isf32));
}

__global__ void __launch_bounds__(256) make_ref(float* __restrict__ ref) {
    int s = blockIdx.x * 256 + threadIdx.x;
    if (s >= S_TOT) return;
    int H, W, st;
    if (s < 5776)      { H = 76; W = 76; st = 0; }
    else if (s < 7220) { H = 38; W = 38; st = 5776; }
    else if (s < 7581) { H = 19; W = 19; st = 7220; }
    else               { H = 1;  W = 20; st = 7581; }
    int r = s - st;
    int i = r / W, j = r % W;
    ref[s * 2 + 0] = (j + 0.5f) / (float)W;
    ref[s * 2 + 1] = (i + 0.5f) / (float)H;
}

__global__ void __launch_bounds__(256) cast_out(const float* __restrict__ x,
                                                void* __restrict__ o, int n,
                                                const int* __restrict__ flag) {
    int isf32 = *flag;
    int i = blockIdx.x * 256 + threadIdx.x;
    if (i >= n) return;
    if (isf32) ((float*)o)[i] = x[i];
    else       ((bf16*)o)[i] = f2b(x[i]);
}

// ---------------- cvt: xb = bf16(x) ----------------
__global__ void __launch_bounds__(256) cvt_x(const float* __restrict__ x,
                                             bf16* __restrict__ xb, int n4) {
    int i = blockIdx.x * 256 + threadIdx.x;
    if (i >= n4) return;
    float4 xv = ((const float4*)x)[i];
    ushort4 xo;
    xo.x = f2b(xv.x); xo.y = f2b(xv.y); xo.z = f2b(xv.z); xo.w = f2b(xv.w);
    ((ushort4*)xb)[i] = xo;
}

// ---------------- cvt: qb = bf16(x + pos) ----------------
__global__ void __launch_bounds__(256) cvt_q(const float* __restrict__ x,
                                             const bf16* __restrict__ pos,
                                             bf16* __restrict__ qb, int n4) {
    int i = blockIdx.x * 256 + threadIdx.x;
    if (i >= n4) return;
    float4 xv = ((const float4*)x)[i];
    ushort4 pv = ((const ushort4*)pos)[i];
    ushort4 qo;
    qo.x = f2b(xv.x + b2f(pv.x));
    qo.y = f2b(xv.y + b2f(pv.y));
    qo.z = f2b(xv.z + b2f(pv.z));
    qo.w = f2b(xv.w + b2f(pv.w));
    ((ushort4*)qb)[i] = qo;
}

// ---------------- all-weights transpose for one layer: 1248 tiles of 32x32 ----------------
__global__ void __launch_bounds__(256) transpose_all(const void* __restrict__ Wv,
                                                     const void* __restrict__ Woff,
                                                     const void* __restrict__ Wa,
                                                     const void* __restrict__ Wo,
                                                     const void* __restrict__ W1,
                                                     const void* __restrict__ W2,
                                                     bf16* __restrict__ Wvt,
                                                     bf16* __restrict__ Wofft,
                                                     bf16* __restrict__ Wat,
                                                     bf16* __restrict__ Wot,
                                                     bf16* __restrict__ W1t,
                                                     bf16* __restrict__ W2t,
                                                     int L, const int* __restrict__ flag) {
    int isf32 = *flag;
    int t = blockIdx.x;
    const void* src; bf16* dst; int K, N; size_t woff;
    if (t < 64)        { src = Wv;   dst = Wvt;   K = 256;  N = 256;  woff = (size_t)L * 65536; }
    else if (t < 128)  { src = Woff; dst = Wofft; K = 256;  N = 256;  woff = (size_t)L * 65536;  t -= 64; }
    else if (t < 160)  { src = Wa;   dst = Wat;   K = 256;  N = 128;  woff = (size_t)L * 32768;  t -= 128; }
    else if (t < 224)  { src = Wo;   dst = Wot;   K = 256;  N = 256;  woff = (size_t)L * 65536;  t -= 160; }
    else if (t < 736)  { src = W1;   dst = W1t;   K = 256;  N = 2048; woff = (size_t)L * 524288; t -= 224; }
    else               { src = W2;   dst = W2t;   K = 2048; N = 256;  woff = (size_t)L * 524288; t -= 736; }
    int ntx = N >> 5;
    int tk = (t / ntx) * 32;
    int tn = (t % ntx) * 32;
    __shared__ float tl[32][33];
    int r = threadIdx.x >> 3;
    int c4 = (threadIdx.x & 7) * 4;
#pragma unroll
    for (int i = 0; i < 4; ++i)
        tl[r][c4 + i] = ldin(src, woff + (size_t)(tk + r) * N + tn + c4 + i, isf32);
    __syncthreads();
#pragma unroll
    for (int i = 0; i < 4; ++i)
        dst[(size_t)(tn + r) * K + tk + c4 + i] = f2b(tl[c4 + i][r]);
}

// ---------------- MFMA GEMM 128x128 (for large-N: FFN1), coalesced LDS epilogue ----------------
__global__ void __launch_bounds__(256) mfma_gemm(const bf16* __restrict__ A,
                                                 const bf16* __restrict__ Wt,
                                                 const void* __restrict__ bias, size_t boff,
                                                 bf16* __restrict__ C,
                                                 int M, int N, int K, int relu,
                                                 const int* __restrict__ flag) {
    int isf32 = *flag;
    __shared__ __align__(16) char smem[128 * 136 * 2];   // 34816 B: As+Bs (20480) / Cs (34816) overlay
    bf16* As = (bf16*)smem;               // 128 x 40
    bf16* Bs = (bf16*)smem + 128 * 40;    // 128 x 40
    bf16* Cs = (bf16*)smem;               // 128 x 136 (16B-aligned rows)
    int tid = threadIdx.x;
    int lane = tid & 63, wave = tid >> 6;
    int wm = (wave & 1) << 6, wn = (wave >> 1) << 6;
    int bm = blockIdx.y * 128, bn = blockIdx.x * 128;
    int q = lane >> 4, l15 = lane & 15;

    v4f acc[4][4];
#pragma unroll
    for (int i = 0; i < 4; ++i)
#pragma unroll
        for (int j = 0; j < 4; ++j) acc[i][j] = (v4f){0.f, 0.f, 0.f, 0.f};

    int ar = tid >> 2;
    int ak = (tid & 3) * 8;
    int brow = tid >> 1;
    int bkh = (tid & 1) * 16;

    for (int k0 = 0; k0 < K; k0 += 32) {
#pragma unroll
        for (int h = 0; h < 2; ++h) {
            int row = ar + 64 * h;
            int gm = bm + row;
            uint4 av = make_uint4(0, 0, 0, 0);
            if (gm < M) av = *(const uint4*)(A + (size_t)gm * K + k0 + ak);
            *(uint4*)&As[row * 40 + ak] = av;
        }
        {
            const bf16* wrow = Wt + (size_t)(bn + brow) * K + k0 + bkh;
            uint4 w0 = *(const uint4*)wrow;
            uint4 w1 = *(const uint4*)(wrow + 8);
            *(uint4*)&Bs[brow * 40 + bkh] = w0;
            *(uint4*)&Bs[brow * 40 + bkh + 8] = w1;
        }
        __syncthreads();
        v8s a_frag[4], b_frag[4];
#pragma unroll
        for (int mi = 0; mi < 4; ++mi)
            a_frag[mi] = *(const v8s*)&As[(wm + mi * 16 + l15) * 40 + q * 8];
#pragma unroll
        for (int ni = 0; ni < 4; ++ni)
            b_frag[ni] = *(const v8s*)&Bs[(wn + ni * 16 + l15) * 40 + q * 8];
#pragma unroll
        for (int mi = 0; mi < 4; ++mi)
#pragma unroll
            for (int ni = 0; ni < 4; ++ni)
                acc[mi][ni] = __builtin_amdgcn_mfma_f32_16x16x32_bf16(
                    a_frag[mi], b_frag[ni], acc[mi][ni], 0, 0, 0);
        __syncthreads();
    }

    // epilogue: bias+relu -> Cs (LDS) -> coalesced 16B global stores
#pragma unroll
    for (int ni = 0; ni < 4; ++ni) {
        int cn = wn + ni * 16 + l15;
        float bv = ldin(bias, boff + bn + cn, isf32);
#pragma unroll
        for (int mi = 0; mi < 4; ++mi) {
#pragma unroll
            for (int r = 0; r < 4; ++r) {
                float v = acc[mi][ni][r] + bv;
                if (relu) v = fmaxf(v, 0.f);
                Cs[(wm + mi * 16 + q * 4 + r) * 136 + cn] = f2b(v);
            }
        }
    }
    __syncthreads();
    {
        int row = tid >> 1, half = tid & 1;
        int gm = bm + row;
        if (gm < M) {
            const bf16* srcp = Cs + row * 136 + half * 64;
            bf16* dstp = C + (size_t)gm * N + bn + half * 64;
#pragma unroll
            for (int i = 0; i < 8; ++i)
                *(uint4*)(dstp + i * 8) = *(const uint4*)(srcp + i * 8);
        }
    }
}

// ---------------- MFMA GEMM 64x64 (small-N / high occupancy), coalesced LDS epilogue ----------------
__global__ void __launch_bounds__(256) mfma_gemm64(const bf16* __restrict__ A,
                                                   const bf16* __restrict__ Wt,
                                                   const void* __restrict__ bias, size_t boff,
                                                   bf16* __restrict__ C,
                                                   int M, int N, int K, int relu,
                                                   const int* __restrict__ flag) {
    int isf32 = *flag;
    __shared__ __align__(16) char smem[64 * 40 * 2 * 2];  // 10240 B: As+Bs / Cs (9216) overlay
    bf16* As = (bf16*)smem;               // 64 x 40
    bf16* Bs = (bf16*)smem + 64 * 40;     // 64 x 40
    bf16* Cs = (bf16*)smem;               // 64 x 72 (16B-aligned rows)
    int tid = threadIdx.x;
    int lane = tid & 63, wave = tid >> 6;
    int wm = (wave & 1) * 32, wn = (wave >> 1) * 32;
    int bm = blockIdx.y * 64, bn = blockIdx.x * 64;
    int q = lane >> 4, l15 = lane & 15;

    v4f acc[2][2];
#pragma unroll
    for (int i = 0; i < 2; ++i)
#pragma unroll
        for (int j = 0; j < 2; ++j) acc[i][j] = (v4f){0.f, 0.f, 0.f, 0.f};

    int srow = tid >> 2;          // 0..63
    int sk = (tid & 3) * 8;       // 0,8,16,24
    bool aok = (bm + srow) < M;
    const bf16* arow = A + (size_t)(aok ? (bm + srow) : 0) * K;
    const bf16* brow = Wt + (size_t)(bn + srow) * K;

    for (int k0 = 0; k0 < K; k0 += 32) {
        uint4 av = make_uint4(0, 0, 0, 0);
        if (aok) av = *(const uint4*)(arow + k0 + sk);
        uint4 bv = *(const uint4*)(brow + k0 + sk);
        *(uint4*)&As[srow * 40 + sk] = av;
        *(uint4*)&Bs[srow * 40 + sk] = bv;
        __syncthreads();
        v8s a_frag[2], b_frag[2];
#pragma unroll
        for (int mi = 0; mi < 2; ++mi)
            a_frag[mi] = *(const v8s*)&As[(wm + mi * 16 + l15) * 40 + q * 8];
#pragma unroll
        for (int ni = 0; ni < 2; ++ni)
            b_frag[ni] = *(const v8s*)&Bs[(wn + ni * 16 + l15) * 40 + q * 8];
#pragma unroll
        for (int mi = 0; mi < 2; ++mi)
#pragma unroll
            for (int ni = 0; ni < 2; ++ni)
                acc[mi][ni] = __builtin_amdgcn_mfma_f32_16x16x32_bf16(
                    a_frag[mi], b_frag[ni], acc[mi][ni], 0, 0, 0);
        __syncthreads();
    }

#pragma unroll
    for (int ni = 0; ni < 2; ++ni) {
        int cn = wn + ni * 16 + l15;
        float bv = ldin(bias, boff + bn + cn, isf32);
#pragma unroll
        for (int mi = 0; mi < 2; ++mi) {
#pragma unroll
            for (int r = 0; r < 4; ++r) {
                float v = acc[mi][ni][r] + bv;
                if (relu) v = fmaxf(v, 0.f);
                Cs[(wm + mi * 16 + q * 4 + r) * 72 + cn] = f2b(v);
            }
        }
    }
    __syncthreads();
    {
        int row = tid >> 2, seg = tid & 3;
        int gm = bm + row;
        if (gm < M) {
            const bf16* srcp = Cs + row * 72 + seg * 16;
            bf16* dstp = C + (size_t)gm * N + bn + seg * 16;
            *(uint4*)(dstp) = *(const uint4*)(srcp);
            *(uint4*)(dstp + 8) = *(const uint4*)(srcp + 8);
        }
    }
}

// ---------------- fallback VALU GEMM ----------------
template<typename TA, int ADDPOS, int RELU>
__global__ void __launch_bounds__(256) gemm_bias(const TA* __restrict__ A,
                                                 const bf16* __restrict__ Apos,
                                                 const void* __restrict__ W, size_t woff,
                                                 const void* __restrict__ bias, size_t boff,
                                                 bf16* __restrict__ C,
                                                 int M, int N, int K,
                                                 const int* __restrict__ flag) {
    int isf32 = *flag;
    __shared__ float As[16][65];
    __shared__ float Bs[16][65];
    int tid = threadIdx.x;
    int tx = tid & 15;
    int ty = tid >> 4;
    int bm = blockIdx.y * 64;
    int bn = blockIdx.x * 64;
    float acc[4][4] = {};
    for (int k0 = 0; k0 < K; k0 += 16) {
#pragma unroll
        for (int e = 0; e < 4; ++e) {
            int idx = tid + e * 256;
            int mm = idx >> 4;
            int kk = idx & 15;
            int gm = bm + mm;
            float av = 0.f;
            if (gm < M) {
                size_t ai = (size_t)gm * K + k0 + kk;
                if (sizeof(TA) == 4) av = ((const float*)A)[ai];
                else                 av = b2f(((const bf16*)A)[ai]);
                if (ADDPOS) av += b2f(Apos[ai]);
            }
            As[kk][mm] = av;
        }
#pragma unroll
        for (int e = 0; e < 4; ++e) {
            int idx = tid + e * 256;
            int kk = idx >> 6;
            int nn = idx & 63;
            int gn = bn + nn;
            Bs[kk][nn] = (gn < N) ? ldin(W, woff + (size_t)(k0 + kk) * N + gn, isf32) : 0.f;
        }
        __syncthreads();
#pragma unroll
        for (int kk = 0; kk < 16; ++kk) {
            float a[4], b[4];
#pragma unroll
            for (int i = 0; i < 4; ++i) a[i] = As[kk][ty + 16 * i];
#pragma unroll
            for (int j = 0; j < 4; ++j) b[j] = Bs[kk][tx + 16 * j];
#pragma unroll
            for (int i = 0; i < 4; ++i)
#pragma unroll
                for (int j = 0; j < 4; ++j) acc[i][j] += a[i] * b[j];
        }
        __syncthreads();
    }
#pragma unroll
    for (int i = 0; i < 4; ++i) {
        int gm = bm + ty + 16 * i;
        if (gm >= M) continue;
#pragma unroll
        for (int j = 0; j < 4; ++j) {
            int gn = bn + tx + 16 * j;
            if (gn >= N) continue;
            float v = acc[i][j] + ldin(bias, boff + gn, isf32);
            if (RELU) v = fmaxf(v, 0.f);
            C[(size_t)gm * N + gn] = f2b(v);
        }
    }
}

// ---------------- MS-deform sampling: 4 rows/block, corner descriptors in LDS ----------------
__global__ void __launch_bounds__(256) msdeform_sample4(const bf16* __restrict__ value,
                                                        const bf16* __restrict__ off,
                                                        const bf16* __restrict__ logits,
                                                        const float* __restrict__ refpts,
                                                        bf16* __restrict__ out) {
    __shared__ float sAttn[4 * 128];
    __shared__ int2 sIW[4 * 520];
    const int LH[4] = {76, 38, 19, 1};
    const int LW[4] = {76, 38, 19, 20};
    const int LS[4] = {0, 5776, 7220, 7581};
    int tid = threadIdx.x;
    int m0 = blockIdx.x * 4;

    for (int i = tid; i < 4 * 128; i += 256) {
        int r = i >> 7, li = i & 127;
        int m = m0 + r;
        int mc = (m < BM) ? m : BM - 1;
        sAttn[i] = b2f(logits[(size_t)mc * 128 + li]);
    }
    __syncthreads();
    if (tid < 32) {
        float* g = sAttn + tid * 16;
        float mx = -1e30f;
#pragma unroll
        for (int i = 0; i < 16; ++i) mx = fmaxf(mx, g[i]);
        float e[16], sm = 0.f;
#pragma unroll
        for (int i = 0; i < 16; ++i) { e[i] = __expf(g[i] - mx); sm += e[i]; }
        float inv = 1.f / sm;
#pragma unroll
        for (int i = 0; i < 16; ++i) g[i] = e[i] * inv;
    }
    __syncthreads();
    for (int i = tid; i < 4 * 128; i += 256) {
        int r = i >> 7, oi = i & 127;
        int m = m0 + r;
        int mc = (m < BM) ? m : BM - 1;
        int b = mc / S_TOT;
        int s = mc - b * S_TOT;
        int h = oi >> 4;
        int l = (oi >> 2) & 3;
        int H = LH[l], W = LW[l], st = LS[l];
        float fW = (float)W, fH = (float)H;
        float refx = refpts[s * 2 + 0];
        float refy = refpts[s * 2 + 1];
        ushort2 ov = *(const ushort2*)(off + (size_t)mc * 256 + oi * 2);
        float a = sAttn[r * 128 + oi];
        float xpix = (refx + b2f(ov.x) / fW) * fW - 0.5f;
        float ypix = (refy + b2f(ov.y) / fH) * fH - 0.5f;
        float x0f = floorf(xpix), y0f = floorf(ypix);
        int x0 = (int)x0f, y0 = (int)y0f;
        float wx1 = xpix - x0f, wy1 = ypix - y0f;
        float wx0 = 1.f - wx1, wy0 = 1.f - wy1;
        int vb = b * (S_TOT * 256) + h * 32;
        int base = r * 520 + h * 65 + (oi & 15) * 4;
#pragma unroll
        for (int c = 0; c < 4; ++c) {
            int cx = c & 1, cy = c >> 1;
            int xi = x0 + cx, yi = y0 + cy;
            float w = (cx ? wx1 : wx0) * (cy ? wy1 : wy0) * a;
            bool valid = (xi >= 0) && (xi <= W - 1) && (yi >= 0) && (yi <= H - 1);
            int xic = min(max(xi, 0), W - 1), yic = min(max(yi, 0), H - 1);
            int2 d;
            d.x = vb + (st + yic * W + xic) * 256;
            d.y = __float_as_int(valid ? w : 0.f);
            sIW[base + c] = d;
        }
    }
    __syncthreads();
    int r = tid >> 6, u = tid & 63;
    int h = u >> 3, d4 = (u & 7) * 4;
    int m = m0 + r;
    int cb = r * 520 + h * 65;
    float acc0 = 0.f, acc1 = 0.f, acc2 = 0.f, acc3 = 0.f;
#pragma unroll 8
    for (int c = 0; c < 64; ++c) {
        int2 p = sIW[cb + c];
        float w = __int_as_float(p.y);
        ushort4 v = *(const ushort4*)(value + p.x + d4);
        acc0 += w * b2f(v.x);
        acc1 += w * b2f(v.y);
        acc2 += w * b2f(v.z);
        acc3 += w * b2f(v.w);
    }
    if (m < BM) {
        ushort4 o;
        o.x = f2b(acc0); o.y = f2b(acc1); o.z = f2b(acc2); o.w = f2b(acc3);
        *(ushort4*)(out + (size_t)m * 256 + h * 32 + d4) = o;
    }
}

// ---------------- residual + LayerNorm: 4 rows/block, 1 wave/row; optional xb and qb=bf16(x+pos) ----------------
__global__ void __launch_bounds__(256) residual_ln4(float* __restrict__ x,
                                                    const bf16* __restrict__ y,
                                                    const void* __restrict__ g, size_t goff,
                                                    const void* __restrict__ beta, size_t boff,
                                                    const int* __restrict__ flag,
                                                    bf16* __restrict__ xb,
                                                    const bf16* __restrict__ pos,
                                                    bf16* __restrict__ qb) {
    int isf32 = *flag;
    int tid = threadIdx.x;
    int r = tid >> 6, lane = tid & 63;
    int m = blockIdx.x * 4 + r;
    if (m >= BM) return;
    size_t o = (size_t)m * 256 + lane * 4;
    float4 xv = *(const float4*)(x + o);
    ushort4 yv = *(const ushort4*)(y + o);
    float r0 = xv.x + b2f(yv.x), r1 = xv.y + b2f(yv.y);
    float r2 = xv.z + b2f(yv.z), r3 = xv.w + b2f(yv.w);
    float sum = r0 + r1 + r2 + r3;
#pragma unroll
    for (int ofs = 32; ofs > 0; ofs >>= 1) sum += __shfl_xor(sum, ofs);
    float mean = sum * (1.f / 256.f);
    float d0 = r0 - mean, d1 = r1 - mean, d2 = r2 - mean, d3 = r3 - mean;
    float vv = d0 * d0 + d1 * d1 + d2 * d2 + d3 * d3;
#pragma unroll
    for (int ofs = 32; ofs > 0; ofs >>= 1) vv += __shfl_xor(vv, ofs);
    float rstd = rsqrtf(vv * (1.f / 256.f) + 1e-5f);
    int c = lane * 4;
    float o0 = d0 * rstd * ldin(g, goff + c + 0, isf32) + ldin(beta, boff + c + 0, isf32);
    float o1 = d1 * rstd * ldin(g, goff + c + 1, isf32) + ldin(beta, boff + c + 1, isf32);
    float o2 = d2 * rstd * ldin(g, goff + c + 2, isf32) + ldin(beta, boff + c + 2, isf32);
    float o3 = d3 * rstd * ldin(g, goff + c + 3, isf32) + ldin(beta, boff + c + 3, isf32);
    *(float4*)(x + o) = make_float4(o0, o1, o2, o3);
    if (xb) {
        ushort4 xo;
        xo.x = f2b(o0); xo.y = f2b(o1); xo.z = f2b(o2); xo.w = f2b(o3);
        *(ushort4*)(xb + o) = xo;
    }
    if (qb) {
        ushort4 pv = *(const ushort4*)(pos + o);
        ushort4 qo;
        qo.x = f2b(o0 + b2f(pv.x));
        qo.y = f2b(o1 + b2f(pv.y));
        qo.z = f2b(o2 + b2f(pv.z));
        qo.w = f2b(o3 + b2f(pv.w));
        *(ushort4*)(qb + o) = qo;
    }
}

// ---------------- host ----------------
extern "C" void kernel_launch(void* const* d_in, const int* in_sizes, int n_in,
                              void* d_out, int out_size, void* d_ws, size_t ws_size,
                              hipStream_t stream) {
    (void)in_sizes; (void)n_in; (void)out_size;
    const size_t MS = (size_t)BM * DMODEL;   // 3,891,712

    char* base = (char*)d_ws;
    int* flag    = (int*)base;    base += 256;
    float* x     = (float*)base;  base += MS * 4;
    bf16* value  = (bf16*)base;   base += MS * 2;
    bf16* attnl  = (bf16*)base;   base += (size_t)BM * 128 * 2;
    bf16* pos    = (bf16*)base;   base += MS * 2;
    bf16* offms  = (bf16*)base;   base += MS * 2;   // off -> msout in place
    bf16* yb     = (bf16*)base;   base += MS * 2;   // also qb (dead before Wo writes)
    size_t base_used = (size_t)(base - (char*)d_ws);

    bf16* xb = (bf16*)base;
    size_t need_fast = base_used + MS * 2
                     + (size_t)2048 * 256 * 2 * 2
                     + (size_t)256 * 256 * 2 * 3
                     + (size_t)128 * 256 * 2
                     + (size_t)S_TOT * 2 * 4 + 1024;
    bool FAST = ws_size >= need_fast;

    bf16 *W1t = nullptr, *W2t = nullptr, *Wvt = nullptr, *Wofft = nullptr, *Wot = nullptr, *Wat = nullptr;
    float* ref;
    bf16* hiddenF = nullptr;
    bool FULLH = false;
    if (FAST) {
        char* p = (char*)xb + MS * 2;
        W1t = (bf16*)p;   p += (size_t)2048 * 256 * 2;
        W2t = (bf16*)p;   p += (size_t)2048 * 256 * 2;
        Wvt = (bf16*)p;   p += (size_t)256 * 256 * 2;
        Wofft = (bf16*)p; p += (size_t)256 * 256 * 2;
        Wot = (bf16*)p;   p += (size_t)256 * 256 * 2;
        Wat = (bf16*)p;   p += (size_t)128 * 256 * 2;
        ref = (float*)p;  p += (size_t)S_TOT * 2 * 4;
        size_t used = (size_t)(p - (char*)d_ws);
        used = (used + 255) & ~(size_t)255;
        if (ws_size >= used + (size_t)BM * 2048 * 2) {
            hiddenF = (bf16*)((char*)d_ws + used);
            FULLH = true;
        }
    } else {
        ref = (float*)base;
    }

    bf16* hidden = FULLH ? hiddenF : value;
    const int CH = FULLH ? BM : 2816;

    detect_dtype<<<1, 256, 0, stream>>>((const unsigned short*)d_in[0], flag);

    {
        int HW0 = 76 * 76, HW1 = 38 * 38, HW2 = 19 * 19;
        int n0 = BATCH * HW0 * 256, n1 = BATCH * HW1 * 256, n2 = BATCH * HW2 * 256;
        pack_level<<<(n0 + 255) / 256, 256, 0, stream>>>(d_in[0], d_in[1], d_in[8], 0, x, pos, HW0, 0, flag);
        pack_level<<<(n1 + 255) / 256, 256, 0, stream>>>(d_in[2], d_in[3], d_in[8], 1, x, pos, HW1, 5776, flag);
        pack_level<<<(n2 + 255) / 256, 256, 0, stream>>>(d_in[4], d_in[5], d_in[8], 2, x, pos, HW2, 7220, flag);
        int nt = BATCH * 20 * 256;
        pack_task<<<(nt + 255) / 256, 256, 0, stream>>>(d_in[6], d_in[7], x, pos, flag);
        make_ref<<<(S_TOT + 255) / 256, 256, 0, stream>>>(ref);
    }

    const int GM64 = (BM + 63) / 64;      // 238
    const int GR4 = (BM + 3) / 4;         // 3801
    const int n4 = (int)(MS / 4);

    if (FAST) {
        cvt_x<<<(n4 + 255) / 256, 256, 0, stream>>>(x, xb, n4);
        cvt_q<<<(n4 + 255) / 256, 256, 0, stream>>>(x, pos, yb, n4);   // qb for layer 0
    }

    for (int L = 0; L < 6; ++L) {
        size_t oW256 = (size_t)L * 256 * 256, ob256 = (size_t)L * 256;
        size_t oW128 = (size_t)L * 256 * 128, ob128 = (size_t)L * 128;
        size_t oW1   = (size_t)L * 256 * 2048, ob1  = (size_t)L * 2048;
        size_t oW2   = (size_t)L * 2048 * 256;

        if (FAST) {
            transpose_all<<<1248, 256, 0, stream>>>(d_in[13], d_in[9], d_in[11], d_in[15], d_in[17], d_in[19],
                                                    Wvt, Wofft, Wat, Wot, W1t, W2t, L, flag);
            bf16* qb = yb;
            mfma_gemm64<<<dim3(4, GM64), 256, 0, stream>>>(xb, Wvt, d_in[14], ob256, value, BM, 256, 256, 0, flag);
            mfma_gemm64<<<dim3(4, GM64), 256, 0, stream>>>(qb, Wofft, d_in[10], ob256, offms, BM, 256, 256, 0, flag);
            mfma_gemm64<<<dim3(2, GM64), 256, 0, stream>>>(qb, Wat, d_in[12], ob128, attnl, BM, 128, 256, 0, flag);

            msdeform_sample4<<<GR4, 256, 0, stream>>>(value, offms, attnl, ref, offms);

            mfma_gemm64<<<dim3(4, GM64), 256, 0, stream>>>(offms, Wot, d_in[16], ob256, yb, BM, 256, 256, 0, flag);
            residual_ln4<<<GR4, 256, 0, stream>>>(x, yb, d_in[21], ob256, d_in[22], ob256, flag, xb, nullptr, nullptr);

            for (int r0 = 0; r0 < BM; r0 += CH) {
                int mc = BM - r0 < CH ? BM - r0 : CH;
                int gmc128 = (mc + 127) / 128;
                int gmc64 = (mc + 63) / 64;
                mfma_gemm<<<dim3(16, gmc128), 256, 0, stream>>>(xb + (size_t)r0 * 256, W1t, d_in[18], ob1,
                                                                hidden, mc, 2048, 256, 1, flag);
                mfma_gemm64<<<dim3(4, gmc64), 256, 0, stream>>>(hidden, W2t, d_in[20], ob256,
                                                                yb + (size_t)r0 * 256, mc, 256, 2048, 0, flag);
            }
            residual_ln4<<<GR4, 256, 0, stream>>>(x, yb, d_in[23], ob256, d_in[24], ob256, flag, xb,
                                                  (L < 5) ? pos : nullptr, (L < 5) ? yb : nullptr);
        } else {
            dim3 g256(4, GM64);
            dim3 g128(2, GM64);
            gemm_bias<float, 0, 0><<<g256, 256, 0, stream>>>(x, nullptr, d_in[13], oW256, d_in[14], ob256,
                                                             value, BM, 256, 256, flag);
            gemm_bias<float, 1, 0><<<g256, 256, 0, stream>>>(x, pos, d_in[9], oW256, d_in[10], ob256,
                                                             offms, BM, 256, 256, flag);
            gemm_bias<float, 1, 0><<<g128, 256, 0, stream>>>(x, pos, d_in[11], oW128, d_in[12], ob128,
                                                             attnl, BM, 128, 256, flag);
            msdeform_sample4<<<GR4, 256, 0, stream>>>(value, offms, attnl, ref, offms);
            gemm_bias<bf16, 0, 0><<<g256, 256, 0, stream>>>(offms, nullptr, d_in[15], oW256, d_in[16], ob256,
                                                            yb, BM, 256, 256, flag);
            residual_ln4<<<GR4, 256, 0, stream>>>(x, yb, d_in[21], ob256, d_in[22], ob256, flag, nullptr, nullptr, nullptr);
            for (int r0 = 0; r0 < BM; r0 += CH) {
                int mc = BM - r0 < CH ? BM - r0 : CH;
                dim3 gh(32, (mc + 63) / 64);
                dim3 go(4, (mc + 63) / 64);
                gemm_bias<float, 0, 1><<<gh, 256, 0, stream>>>(x + (size_t)r0 * 256, nullptr, d_in[17], oW1,
                                                               d_in[18], ob1, hidden, mc, 2048, 256, flag);
                gemm_bias<bf16, 0, 0><<<go, 256, 0, stream>>>(hidden, nullptr, d_in[19], oW2, d_in[20], ob256,
                                                              yb + (size_t)r0 * 256, mc, 256, 2048, flag);
            }
            residual_ln4<<<GR4, 256, 0, stream>>>(x, yb, d_in[23], ob256, d_in[24], ob256, flag, nullptr, nullptr, nullptr);
        }
    }

    cast_out<<<((int)MS + 255) / 256, 256, 0, stream>>>(x, d_out, (int)MS, flag);
}